// Round 7
// baseline (2321.375 us; speedup 1.0000x reference)
//
#include <hip/hip_runtime.h>
#include <stdint.h>

#define B_ 16
#define S_ 512
#define D_ 1024
#define H4 512
#define G_ 256

typedef unsigned short u16;
using short8 = __attribute__((ext_vector_type(8))) short;
using f32x4  = __attribute__((ext_vector_type(4))) float;

__device__ __forceinline__ u16 f2bf(float f){
  unsigned int u = __float_as_uint(f);
  u += 0x7fffu + ((u >> 16) & 1u);
  return (u16)(u >> 16);
}
__device__ __forceinline__ float bf2f(u16 h){
  return __uint_as_float(((unsigned int)h) << 16);
}

// ---------------- single-dispatch f32 -> bf16 convert over all segments ----------------
struct CvtSegs {
  const float4* src[14];
  short4* dst[14];
  int blk0[15];
};
__global__ __launch_bounds__(256) void cvt_multi(CvtSegs cs){
  int blk = blockIdx.x;
  int s = 0;
  #pragma unroll
  for (int k = 0; k < 14; ++k) if (cs.blk0[k + 1] <= blk) s = k + 1;
  int i = (blk - cs.blk0[s]) * 256 + threadIdx.x;
  float4 v = cs.src[s][i];
  short4 o;
  o.x = (short)f2bf(v.x); o.y = (short)f2bf(v.y);
  o.z = (short)f2bf(v.z); o.w = (short)f2bf(v.w);
  cs.dst[s][i] = o;
}

// ---------------- Whh -> gate-interleaved bf16: out[mat][c=4j+g][k] = Whh[mat][g*128+j][k] ----
__global__ __launch_bounds__(256) void cvt_whh(const float* m0, const float* m1,
                                               const float* m2, const float* m3,
                                               u16* out){
  int e = blockIdx.x * 256 + threadIdx.x;     // 32768 total, 8 elems each
  int row = e >> 4;                           // global out row among 4*512
  int kk = (e & 15) * 8;
  int mat = row >> 9, c = row & 511;
  const float* src = (mat == 0 ? m0 : mat == 1 ? m1 : mat == 2 ? m2 : m3)
                     + ((c & 3) * 128 + (c >> 2)) * 128 + kk;
  u16* dst = out + (size_t)row * 128 + kk;
  float4 v0 = *(const float4*)src, v1 = *(const float4*)(src + 4);
  dst[0] = f2bf(v0.x); dst[1] = f2bf(v0.y); dst[2] = f2bf(v0.z); dst[3] = f2bf(v0.w);
  dst[4] = f2bf(v1.x); dst[5] = f2bf(v1.y); dst[6] = f2bf(v1.z); dst[7] = f2bf(v1.w);
}

// ---------------- LSTM bias sums (bih+bhh) ----------------
__global__ __launch_bounds__(256) void bias_prep(const float* a,const float* b,const float* c,const float* d,
                                                 const float* e,const float* f,const float* g,const float* h,
                                                 float* out){
  int i = blockIdx.x * 256 + threadIdx.x;
  if (i >= 2048) return;
  int p = i >> 9, k = i & 511;
  const float* x1 = (p==0)?a:(p==1)?c:(p==2)?e:g;
  const float* x2 = (p==0)?b:(p==1)?d:(p==2)?f:h;
  out[i] = x1[k] + x2[k];
}

// ---------------- MFMA BT-GEMM body (256 thr, 64x64 tile) ----------------
// ACT: 0=none, 1=relu.  PERM: 0 = row-major out, 2 = gate-interleaved X layout
template<int ACT, bool OUT_BF16, int PERM, bool RESID>
__device__ __forceinline__ void gemm_bt_body(
    const u16* __restrict__ A, const u16* __restrict__ W,
    const float* __restrict__ bias, const u16* __restrict__ resid,
    void* __restrict__ outp, int M, int N, int K,
    long sA, long sW, long sO, int bx, int by, int bz)
{
  const u16* Ab = A + (long)bz * sA;
  const u16* Wb = W + (long)bz * sW;
  const int bm0 = by * 64, bn0 = bx * 64;
  const int tid = threadIdx.x;
  const int l = tid & 63, wid = tid >> 6;
  const int wm = (wid >> 1) * 32, wn = (wid & 1) * 32;
  const int lr = l & 15, lk8 = (l >> 4) * 8;

  const f32x4 z4 = {0.f, 0.f, 0.f, 0.f};
  f32x4 acc[2][2] = {{z4, z4}, {z4, z4}};

  const u16* Ap0 = Ab + (long)(bm0 + wm + lr) * K + lk8;
  const u16* Wp0 = Wb + (long)(bn0 + wn + lr) * K + lk8;
  for (int k0 = 0; k0 < K; k0 += 32) {
    short8 a0 = *reinterpret_cast<const short8*>(Ap0 + k0);
    short8 a1 = *reinterpret_cast<const short8*>(Ap0 + (long)16 * K + k0);
    short8 b0 = *reinterpret_cast<const short8*>(Wp0 + k0);
    short8 b1 = *reinterpret_cast<const short8*>(Wp0 + (long)16 * K + k0);
    acc[0][0] = __builtin_amdgcn_mfma_f32_16x16x32_bf16(a0, b0, acc[0][0], 0, 0, 0);
    acc[0][1] = __builtin_amdgcn_mfma_f32_16x16x32_bf16(a0, b1, acc[0][1], 0, 0, 0);
    acc[1][0] = __builtin_amdgcn_mfma_f32_16x16x32_bf16(a1, b0, acc[1][0], 0, 0, 0);
    acc[1][1] = __builtin_amdgcn_mfma_f32_16x16x32_bf16(a1, b1, acc[1][1], 0, 0, 0);
  }
  #pragma unroll
  for (int mt = 0; mt < 2; ++mt)
  #pragma unroll
  for (int nt = 0; nt < 2; ++nt) {
    int n = bn0 + wn + 16 * nt + lr;
    float bv = bias ? bias[n] : 0.f;
    #pragma unroll
    for (int r = 0; r < 4; ++r) {
      int m = bm0 + wm + 16 * mt + (l >> 4) * 4 + r;
      float v = acc[mt][nt][r] + bv;
      if (ACT == 1) v = fmaxf(v, 0.f);
      if (RESID) v += bf2f(resid[(long)m * N + n]);
      long oi;
      if (PERM == 2) {
        int t = m & 511, b = m >> 9;
        oi = (long)((t * 16 + b) * 128 + (n & 127)) * 4 + (n >> 7);
      } else {
        oi = (long)bz * sO + (long)m * N + n;
      }
      if (OUT_BF16) ((u16*)outp)[oi] = f2bf(v);
      else          ((float*)outp)[oi] = v;
    }
  }
}

template<int ACT, bool OUT_BF16, int PERM, bool RESID>
__global__ __launch_bounds__(256) void gemm_bt(
    const u16* __restrict__ A, const u16* __restrict__ W,
    const float* __restrict__ bias, const u16* __restrict__ resid,
    void* __restrict__ outp, int M, int N, int K,
    long sA, long sW, long sO)
{
  gemm_bt_body<ACT, OUT_BF16, PERM, RESID>(A, W, bias, resid, outp, M, N, K,
                                           sA, sW, sO, blockIdx.x, blockIdx.y, blockIdx.z);
}

// ---------------- 8-wave BT-GEMM body (512 thr, 64x128 tile, bf16 out, bias) ----------------
__device__ __forceinline__ void gemm_bt_body8(
    const u16* __restrict__ A, const u16* __restrict__ W,
    const float* __restrict__ bias, u16* __restrict__ out,
    int N, int K, int bx, int by)
{
  const int bm0 = by * 64, bn0 = bx * 128;
  const int tid = threadIdx.x;
  const int l = tid & 63, wid = tid >> 6;
  const int wm = (wid >> 2) * 32, wn = (wid & 3) * 32;
  const int lr = l & 15, lk8 = (l >> 4) * 8;

  const f32x4 z4 = {0.f, 0.f, 0.f, 0.f};
  f32x4 acc[2][2] = {{z4, z4}, {z4, z4}};

  const u16* Ap0 = A + (long)(bm0 + wm + lr) * K + lk8;
  const u16* Wp0 = W + (long)(bn0 + wn + lr) * K + lk8;
  for (int k0 = 0; k0 < K; k0 += 32) {
    short8 a0 = *reinterpret_cast<const short8*>(Ap0 + k0);
    short8 a1 = *reinterpret_cast<const short8*>(Ap0 + (long)16 * K + k0);
    short8 b0 = *reinterpret_cast<const short8*>(Wp0 + k0);
    short8 b1 = *reinterpret_cast<const short8*>(Wp0 + (long)16 * K + k0);
    acc[0][0] = __builtin_amdgcn_mfma_f32_16x16x32_bf16(a0, b0, acc[0][0], 0, 0, 0);
    acc[0][1] = __builtin_amdgcn_mfma_f32_16x16x32_bf16(a0, b1, acc[0][1], 0, 0, 0);
    acc[1][0] = __builtin_amdgcn_mfma_f32_16x16x32_bf16(a1, b0, acc[1][0], 0, 0, 0);
    acc[1][1] = __builtin_amdgcn_mfma_f32_16x16x32_bf16(a1, b1, acc[1][1], 0, 0, 0);
  }
  #pragma unroll
  for (int mt = 0; mt < 2; ++mt)
  #pragma unroll
  for (int nt = 0; nt < 2; ++nt) {
    int n = bn0 + wn + 16 * nt + lr;
    float bv = bias[n];
    #pragma unroll
    for (int r = 0; r < 4; ++r) {
      int m = bm0 + wm + 16 * mt + (l >> 4) * 4 + r;
      out[(long)m * N + n] = f2bf(acc[mt][nt][r] + bv);
    }
  }
}

// ---------------- LSTM scan v5: 4 blocks/dir x 4 batches, bf16 X, h ring + staged flush ----------------
// X: [t][b(16)][j(128)][gate(4)] bf16.  Wp: gate-interleaved [c=4j+g][k] bf16.
// Wave w covers z-rows [64w,64w+64): lane holds (i,f,g,o) quad for j=16w+4nt+lk, batch=lr&3.
// Lanes lr>=4 duplicate batch lr&3 (same cachelines; LDS writes guarded to lr<4).
__device__ __forceinline__ void lstm_scan5_body(
    const u16* __restrict__ X, const u16* __restrict__ Wp,
    u16* __restrict__ Hout, int dir, int bat0)
{
  __shared__ __align__(16) u16 hbuf[8][4][128];    // 8-slot ring, 4 batches, XOR chunk swizzle (8KB)

  const int tid = threadIdx.x;
  const int l = tid & 63, w = tid >> 6;            // 8 waves
  const int lr = l & 15, lk = l >> 4;
  const int br = lr & 3;

  short8 wfrag[4][4];
  #pragma unroll
  for (int nt = 0; nt < 4; ++nt)
    #pragma unroll
    for (int ks = 0; ks < 4; ++ks)
      wfrag[nt][ks] = *reinterpret_cast<const short8*>(
          Wp + (64 * w + 16 * nt + lr) * 128 + 32 * ks + 8 * lk);

  for (int i = tid; i < 8 * 4 * 128; i += 512) ((u16*)hbuf)[i] = 0;

  float cst[4] = {0.f, 0.f, 0.f, 0.f};
  const f32x4 z4 = {0.f, 0.f, 0.f, 0.f};

  auto ldX = [&](int t, short4 (&xr)[4]) {
    int ta = dir ? (S_ - 1 - t) : t;
    const u16* p = X + (size_t)(ta * 16 + bat0 + br) * 512 + 64 * w + 4 * lk;
    #pragma unroll
    for (int nt = 0; nt < 4; ++nt)
      xr[nt] = *reinterpret_cast<const short4*>(p + 16 * nt);
  };

  short4 s0[4], s1[4], s2[4], s3[4];
  ldX(0, s0); ldX(1, s1); ldX(2, s2); ldX(3, s3);

  __syncthreads();

  auto flush = [&](int m) {
    int s = tid >> 6, b2 = (tid >> 4) & 3, c = tid & 15;
    short8 v = *reinterpret_cast<const short8*>(&hbuf[s][b2][(c ^ (b2 << 2)) << 3]);
    int u = 8 * m + ((s - 1) & 7);
    int ta = dir ? (S_ - 1 - u) : u;
    *reinterpret_cast<short8*>(&Hout[((size_t)(bat0 + b2) * S_ + ta) * 256 + dir * 128 + c * 8]) = v;
    __builtin_amdgcn_s_barrier();
  };

  auto period = [&](int t, short4 (&xc)[4], int tload) {
    const int rs = t & 7, ws = (t + 1) & 7;
    short8 hf[4];
    #pragma unroll
    for (int ks = 0; ks < 4; ++ks)
      hf[ks] = *reinterpret_cast<const short8*>(&hbuf[rs][br][((4 * ks + lk) ^ (br << 2)) << 3]);
    f32x4 acc[4] = {z4, z4, z4, z4};
    #pragma unroll
    for (int nt = 0; nt < 4; ++nt)
      #pragma unroll
      for (int ks = 0; ks < 4; ++ks)
        acc[nt] = __builtin_amdgcn_mfma_f32_16x16x32_bf16(wfrag[nt][ks], hf[ks], acc[nt], 0, 0, 0);
    float zi[4], zf[4], zg[4], zo[4];
    #pragma unroll
    for (int nt = 0; nt < 4; ++nt) {
      zi[nt] = acc[nt][0] + bf2f((u16)xc[nt].x);
      zf[nt] = acc[nt][1] + bf2f((u16)xc[nt].y);
      zg[nt] = acc[nt][2] + bf2f((u16)xc[nt].z);
      zo[nt] = acc[nt][3] + bf2f((u16)xc[nt].w);
    }
    if (tload < S_) ldX(tload, xc);
    #pragma unroll
    for (int nt = 0; nt < 4; ++nt) {
      float si = __fdividef(1.f, 1.f + __expf(-zi[nt]));
      float sf = __fdividef(1.f, 1.f + __expf(-zf[nt]));
      float so = __fdividef(1.f, 1.f + __expf(-zo[nt]));
      float eg = __expf(2.f * zg[nt]);
      float tg = 1.f - __fdividef(2.f, eg + 1.f);
      cst[nt] = sf * cst[nt] + si * tg;
      float ec = __expf(2.f * cst[nt]);
      float tc = 1.f - __fdividef(2.f, ec + 1.f);
      u16 hb = f2bf(so * tc);
      if (lr < 4) {
        int j = 16 * w + 4 * nt + lk;
        hbuf[ws][lr][(((j >> 3) ^ (lr << 2)) << 3) + (j & 7)] = hb;
      }
    }
    asm volatile("s_waitcnt lgkmcnt(0)" ::: "memory");
    __builtin_amdgcn_s_barrier();
    if (rs == 7) flush(t >> 3);
  };

  for (int t = 0; t < S_; t += 4) {
    period(t,     s0, t + 4);
    period(t + 1, s1, t + 5);
    period(t + 2, s2, t + 6);
    period(t + 3, s3, t + 7);
  }
}

// ---------------- fused dispatch: blocks 0..7 = scan(dir,batgrp), blocks 8.. = BT-GEMM ----------------
__global__ __launch_bounds__(512, 1) void scan_fused(
    const u16* __restrict__ Xf, const u16* __restrict__ Xb,
    const u16* __restrict__ WpF, const u16* __restrict__ WpB,
    u16* __restrict__ Hout,
    const u16* __restrict__ gA, const u16* __restrict__ gW,
    const float* __restrict__ gb, u16* __restrict__ gOut, int gK)
{
  if (blockIdx.x < 8) {
    int dir = blockIdx.x & 1, bat0 = (blockIdx.x >> 1) * 4;
    lstm_scan5_body(dir ? Xb : Xf, dir ? WpB : WpF, Hout, dir, bat0);
  } else {
    int bi = blockIdx.x - 8;
    gemm_bt_body8(gA, gW, gb, gOut, 256, gK, bi & 1, bi >> 1);
  }
}

// ---------------- attention: sigmoid + diag/adj mask + row-normalize ----------------
__global__ __launch_bounds__(256) void attn_norm(
    const float* __restrict__ sc, const float* __restrict__ adj, u16* __restrict__ abf)
{
  int bz = blockIdx.y;
  int i = blockIdx.x * 4 + (threadIdx.x >> 6);
  int l = threadIdx.x & 63;
  const float* srow = sc  + ((long)bz * 512 + i) * 512;
  const float* arow = adj + ((long)bz * 512 + i) * 512;
  float av[8]; float sum = 0.f;
  #pragma unroll
  for (int k = 0; k < 8; ++k) {
    int jj = l + 64 * k;
    float sg = __fdividef(1.f, 1.f + __expf(-srow[jj]));
    float v = (jj == i) ? (sg + 1e-5f) : sg * arow[jj];
    av[k] = v; sum += v;
  }
  #pragma unroll
  for (int off = 32; off; off >>= 1) sum += __shfl_xor(sum, off);
  float r = __fdividef(1.f, sum);
  u16* orow = abf + ((long)bz * 512 + i) * 512;
  #pragma unroll
  for (int k = 0; k < 8; ++k) orow[l + 64 * k] = f2bf(av[k] * r);
}

// ---------------- transpose g: [B][512][256] -> [B][256][512] ----------------
__global__ __launch_bounds__(256) void transpose_g(const u16* __restrict__ in, u16* __restrict__ out)
{
  __shared__ u16 tile[32][33];
  int bz = blockIdx.z;
  int s0 = blockIdx.x * 32, d0 = blockIdx.y * 32;
  int tx = threadIdx.x & 31, ty = threadIdx.x >> 5;
  const u16* ip = in + (long)bz * 512 * 256;
  u16* op = out + (long)bz * 256 * 512;
  #pragma unroll
  for (int k = 0; k < 32; k += 8) tile[ty + k][tx] = ip[(long)(s0 + ty + k) * 256 + d0 + tx];
  __syncthreads();
  #pragma unroll
  for (int k = 0; k < 32; k += 8) op[(long)(d0 + ty + k) * 512 + s0 + tx] = tile[tx][ty + k];
}

// ---------------- mean over S of concat[lstm_out, g_final] -> d_out[32..] ----------------
__global__ __launch_bounds__(256) void mean_cat(
    const u16* __restrict__ lstm, const u16* __restrict__ gf, float* __restrict__ dout)
{
  int b = blockIdx.x;
  for (int cc = threadIdx.x; cc < 512; cc += 256) {
    const u16* src = (cc < 256) ? (lstm + (long)b * 512 * 256 + cc)
                                : (gf   + (long)b * 512 * 256 + (cc - 256));
    float s = 0.f;
    for (int t = 0; t < 512; ++t) s += bf2f(src[(long)t * 256]);
    dout[32 + b * 512 + cc] = s * (1.f / 512.f);
  }
}

// ---------------- head: fcA -> leaky -> fcB -> leaky -> fcC ----------------
__global__ __launch_bounds__(256) void head_kernel(
    const float* __restrict__ hidden,
    const float* __restrict__ fcA_W, const float* __restrict__ fcA_b,
    const float* __restrict__ fcB_W, const float* __restrict__ fcB_b,
    const float* __restrict__ fcC_W, const float* __restrict__ fcC_b,
    float* __restrict__ y)
{
  __shared__ float hb[16 * 512];
  __shared__ float ab[16 * 128];
  __shared__ float bb[16 * 32];
  int tid = threadIdx.x;
  for (int i = tid; i < 8192; i += 256) hb[i] = hidden[i];
  __syncthreads();
  for (int o = tid; o < 2048; o += 256) {
    int b = o >> 7, jj = o & 127;
    float acc = fcA_b[jj];
    const float* wrow = fcA_W + jj * 512;
    const float* hrow = hb + b * 512;
    for (int k = 0; k < 512; ++k) acc += hrow[k] * wrow[k];
    ab[o] = acc > 0.f ? acc : 0.1f * acc;
  }
  __syncthreads();
  for (int o = tid; o < 512; o += 256) {
    int b = o >> 5, jj = o & 31;
    float acc = fcB_b[jj];
    for (int k = 0; k < 128; ++k) acc += ab[b * 128 + k] * fcB_W[jj * 128 + k];
    bb[o] = acc > 0.f ? acc : 0.1f * acc;
  }
  __syncthreads();
  if (tid < 32) {
    int b = tid >> 1, jj = tid & 1;
    float acc = fcC_b[jj];
    for (int k = 0; k < 32; ++k) acc += bb[b * 32 + k] * fcC_W[jj * 32 + k];
    y[b * 2 + jj] = acc;
  }
}

extern "C" void kernel_launch(void* const* d_in, const int* in_sizes, int n_in,
                              void* d_out, int out_size, void* d_ws, size_t ws_size,
                              hipStream_t stream)
{
  const float* x       = (const float*)d_in[0];
  const float* adj     = (const float*)d_in[1];
  const float* l0f_Wih = (const float*)d_in[2];
  const float* l0f_Whh = (const float*)d_in[3];
  const float* l0f_bih = (const float*)d_in[4];
  const float* l0f_bhh = (const float*)d_in[5];
  const float* l0b_Wih = (const float*)d_in[6];
  const float* l0b_Whh = (const float*)d_in[7];
  const float* l0b_bih = (const float*)d_in[8];
  const float* l0b_bhh = (const float*)d_in[9];
  const float* l1f_Wih = (const float*)d_in[10];
  const float* l1f_Whh = (const float*)d_in[11];
  const float* l1f_bih = (const float*)d_in[12];
  const float* l1f_bhh = (const float*)d_in[13];
  const float* l1b_Wih = (const float*)d_in[14];
  const float* l1b_Whh = (const float*)d_in[15];
  const float* l1b_bih = (const float*)d_in[16];
  const float* l1b_bhh = (const float*)d_in[17];
  const float* fc1_W   = (const float*)d_in[18];
  const float* fc1_b   = (const float*)d_in[19];
  const float* wattn_W = (const float*)d_in[20];
  const float* wattn_b = (const float*)d_in[21];
  const float* lin0_W  = (const float*)d_in[22];
  const float* lin0_b  = (const float*)d_in[23];
  const float* lin1_W  = (const float*)d_in[24];
  const float* lin1_b  = (const float*)d_in[25];
  const float* linf_W  = (const float*)d_in[26];
  const float* linf_b  = (const float*)d_in[27];
  const float* fcA_W   = (const float*)d_in[28];
  const float* fcA_b   = (const float*)d_in[29];
  const float* fcB_W   = (const float*)d_in[30];
  const float* fcB_b   = (const float*)d_in[31];
  const float* fcC_W   = (const float*)d_in[32];
  const float* fcC_b   = (const float*)d_in[33];

  char* wp = (char*)d_ws;
  auto alloc = [&](size_t n) -> void* { void* p = wp; wp += (n + 255) & ~(size_t)255; return p; };

  u16* x_bf     = (u16*)alloc((size_t)B_ * S_ * D_ * 2);
  u16* w0f_ih   = (u16*)alloc((size_t)512 * 1024 * 2);
  u16* w0b_ih   = (u16*)alloc((size_t)512 * 1024 * 2);
  u16* w1f_ih   = (u16*)alloc((size_t)512 * 256 * 2);
  u16* w1b_ih   = (u16*)alloc((size_t)512 * 256 * 2);
  u16* wI       = (u16*)alloc((size_t)4 * 512 * 128 * 2);   // gate-interleaved Whh x4
  u16* wfc1     = (u16*)alloc((size_t)256 * 1024 * 2);
  u16* wattn_bf = (u16*)alloc((size_t)4 * 256 * 256 * 2);
  u16* wlin0_bf = (u16*)alloc((size_t)4 * 256 * 256 * 2);
  u16* wlin1_bf = (u16*)alloc((size_t)4 * 256 * 256 * 2);
  u16* wlinf_bf = (u16*)alloc((size_t)256 * 256 * 2);
  float* bias4  = (float*)alloc((size_t)2048 * 4);
  u16* X0f      = (u16*)alloc((size_t)S_ * 16 * 512 * 2);
  u16* X0b      = (u16*)alloc((size_t)S_ * 16 * 512 * 2);
  u16* h0       = (u16*)alloc((size_t)B_ * S_ * 256 * 2);
  u16* lstm_out = (u16*)alloc((size_t)B_ * S_ * 256 * 2);
  u16* gA       = (u16*)alloc((size_t)B_ * S_ * 256 * 2);
  u16* gB       = (u16*)alloc((size_t)B_ * S_ * 256 * 2);
  u16* qb       = (u16*)alloc((size_t)B_ * S_ * 256 * 2);
  u16* gT       = (u16*)alloc((size_t)B_ * S_ * 256 * 2);
  u16* t1       = (u16*)alloc((size_t)B_ * S_ * 256 * 2);
  u16* t2       = (u16*)alloc((size_t)B_ * S_ * 256 * 2);
  float* sc     = (float*)alloc((size_t)B_ * S_ * S_ * 4);
  u16* abf      = (u16*)alloc((size_t)B_ * S_ * S_ * 2);

  // ---- conversions ----
  CvtSegs cs;
  int nb = 0, si = 0;
  auto seg = [&](const float* s, u16* d, int n) {
    cs.src[si] = (const float4*)s; cs.dst[si] = (short4*)d;
    cs.blk0[si] = nb; nb += (n / 4 + 255) / 256; ++si;
  };
  seg(x, x_bf, B_ * S_ * D_);
  seg(l0f_Wih, w0f_ih, 512 * 1024);
  seg(l0b_Wih, w0b_ih, 512 * 1024);
  seg(l1f_Wih, w1f_ih, 512 * 256);
  seg(l1b_Wih, w1b_ih, 512 * 256);
  seg(fc1_W, wfc1, 256 * 1024);
  seg(wattn_W, wattn_bf, 4 * 256 * 256);
  seg(lin0_W, wlin0_bf, 4 * 256 * 256);
  seg(lin1_W, wlin1_bf, 4 * 256 * 256);
  seg(linf_W, wlinf_bf, 256 * 256);
  for (int k = si; k <= 14; ++k) cs.blk0[k] = nb;
  cvt_multi<<<nb, 256, 0, stream>>>(cs);
  cvt_whh<<<128, 256, 0, stream>>>(l0f_Whh, l0b_Whh, l1f_Whh, l1b_Whh, wI);
  bias_prep<<<8, 256, 0, stream>>>(l0f_bih, l0f_bhh, l0b_bih, l0b_bhh,
                                   l1f_bih, l1f_bhh, l1b_bih, l1b_bhh, bias4);

  // ---- LSTM layer 0: input projections (PERM2 -> bf16 X), then scan (+fc1 GEMM fused) ----
  gemm_bt<0, true, 2, false><<<dim3(8, 128, 1), 256, 0, stream>>>(
      x_bf, w0f_ih, bias4 + 0, nullptr, X0f, 8192, 512, 1024, 0, 0, 0);
  gemm_bt<0, true, 2, false><<<dim3(8, 128, 1), 256, 0, stream>>>(
      x_bf, w0b_ih, bias4 + 512, nullptr, X0b, 8192, 512, 1024, 0, 0, 0);
  scan_fused<<<8 + 256, 512, 0, stream>>>(X0f, X0b, wI + 0 * 65536, wI + 1 * 65536, h0,
                                          x_bf, wfc1, fc1_b, gA, 1024);
  // ---- LSTM layer 1 (+ GAT layer-0 wattn GEMM fused) ----
  gemm_bt<0, true, 2, false><<<dim3(8, 128, 1), 256, 0, stream>>>(
      h0, w1f_ih, bias4 + 1024, nullptr, X0f, 8192, 512, 256, 0, 0, 0);
  gemm_bt<0, true, 2, false><<<dim3(8, 128, 1), 256, 0, stream>>>(
      h0, w1b_ih, bias4 + 1536, nullptr, X0b, 8192, 512, 256, 0, 0, 0);
  scan_fused<<<8 + 256, 512, 0, stream>>>(X0f, X0b, wI + 2 * 65536, wI + 3 * 65536, lstm_out,
                                          gA, wattn_bf, wattn_b, qb, 256);

  // ---- GAT ----
  u16* gcur = gA; u16* gnext = gB;
  for (int lyr = 0; lyr < 4; ++lyr) {
    if (lyr > 0)
      gemm_bt<0, true, 0, false><<<dim3(4, 128, 1), 256, 0, stream>>>(
          gcur, wattn_bf + lyr * 65536, wattn_b + lyr * 256, nullptr, qb, 8192, 256, 256, 0, 0, 0);
    gemm_bt<0, false, 0, false><<<dim3(8, 8, 16), 256, 0, stream>>>(
        qb, gcur, nullptr, nullptr, sc, 512, 512, 256, 131072, 131072, 262144);
    attn_norm<<<dim3(128, 16), 256, 0, stream>>>(sc, adj, abf);
    transpose_g<<<dim3(16, 8, 16), 256, 0, stream>>>(gcur, gT);
    gemm_bt<0, true, 0, false><<<dim3(4, 8, 16), 256, 0, stream>>>(
        abf, gT, nullptr, nullptr, t1, 512, 256, 512, 262144, 131072, 131072);
    gemm_bt<1, true, 0, false><<<dim3(4, 128, 1), 256, 0, stream>>>(
        t1, wlin0_bf + lyr * 65536, lin0_b + lyr * 256, nullptr, t2, 8192, 256, 256, 0, 0, 0);
    gemm_bt<1, true, 0, true><<<dim3(4, 128, 1), 256, 0, stream>>>(
        t2, wlin1_bf + lyr * 65536, lin1_b + lyr * 256, gcur, gnext, 8192, 256, 256, 0, 0, 0);
    u16* tmp = gcur; gcur = gnext; gnext = tmp;
  }
  gemm_bt<0, true, 0, false><<<dim3(4, 128, 1), 256, 0, stream>>>(
      gcur, wlinf_bf, linf_b, nullptr, t2, 8192, 256, 256, 0, 0, 0);

  // ---- pool + head ----
  mean_cat<<<16, 256, 0, stream>>>(lstm_out, t2, (float*)d_out);
  head_kernel<<<1, 256, 0, stream>>>((const float*)d_out + 32,
                                     fcA_W, fcA_b, fcB_W, fcB_b, fcC_W, fcC_b,
                                     (float*)d_out);
}

// Round 8
// 1359.537 us; speedup vs baseline: 1.7075x; 1.7075x over previous
//
#include <hip/hip_runtime.h>
#include <stdint.h>

#define B_ 16
#define S_ 512
#define D_ 1024
#define H4 512
#define G_ 256

typedef unsigned short u16;
using short8 = __attribute__((ext_vector_type(8))) short;
using f32x4  = __attribute__((ext_vector_type(4))) float;

__device__ __forceinline__ u16 f2bf(float f){
  unsigned int u = __float_as_uint(f);
  u += 0x7fffu + ((u >> 16) & 1u);
  return (u16)(u >> 16);
}
__device__ __forceinline__ float bf2f(u16 h){
  return __uint_as_float(((unsigned int)h) << 16);
}

// ---------------- single-dispatch f32 -> bf16 convert over all segments ----------------
struct CvtSegs {
  const float4* src[14];
  short4* dst[14];
  int blk0[15];
};
__global__ __launch_bounds__(256) void cvt_multi(CvtSegs cs){
  int blk = blockIdx.x;
  int s = 0;
  #pragma unroll
  for (int k = 0; k < 14; ++k) if (cs.blk0[k + 1] <= blk) s = k + 1;
  int i = (blk - cs.blk0[s]) * 256 + threadIdx.x;
  float4 v = cs.src[s][i];
  short4 o;
  o.x = (short)f2bf(v.x); o.y = (short)f2bf(v.y);
  o.z = (short)f2bf(v.z); o.w = (short)f2bf(v.w);
  cs.dst[s][i] = o;
}

// ---------------- LSTM bias sums (bih+bhh) ----------------
__global__ __launch_bounds__(256) void bias_prep(const float* a,const float* b,const float* c,const float* d,
                                                 const float* e,const float* f,const float* g,const float* h,
                                                 float* out){
  int i = blockIdx.x * 256 + threadIdx.x;
  if (i >= 2048) return;
  int p = i >> 9, k = i & 511;
  const float* x1 = (p==0)?a:(p==1)?c:(p==2)?e:g;
  const float* x2 = (p==0)?b:(p==1)?d:(p==2)?f:h;
  out[i] = x1[k] + x2[k];
}

// ---------------- MFMA BT-GEMM body (256 thr, 64x64 tile) ----------------
// ACT: 0=none, 1=relu.  PERM: 0 = row-major out, 2 = gate-interleaved X layout
template<int ACT, bool OUT_BF16, int PERM, bool RESID>
__device__ __forceinline__ void gemm_bt_body(
    const u16* __restrict__ A, const u16* __restrict__ W,
    const float* __restrict__ bias, const u16* __restrict__ resid,
    void* __restrict__ outp, int M, int N, int K,
    long sA, long sW, long sO, int bx, int by, int bz)
{
  const u16* Ab = A + (long)bz * sA;
  const u16* Wb = W + (long)bz * sW;
  const int bm0 = by * 64, bn0 = bx * 64;
  const int tid = threadIdx.x;
  const int l = tid & 63, wid = tid >> 6;
  const int wm = (wid >> 1) * 32, wn = (wid & 1) * 32;
  const int lr = l & 15, lk8 = (l >> 4) * 8;

  const f32x4 z4 = {0.f, 0.f, 0.f, 0.f};
  f32x4 acc[2][2] = {{z4, z4}, {z4, z4}};

  const u16* Ap0 = Ab + (long)(bm0 + wm + lr) * K + lk8;
  const u16* Wp0 = Wb + (long)(bn0 + wn + lr) * K + lk8;
  for (int k0 = 0; k0 < K; k0 += 32) {
    short8 a0 = *reinterpret_cast<const short8*>(Ap0 + k0);
    short8 a1 = *reinterpret_cast<const short8*>(Ap0 + (long)16 * K + k0);
    short8 b0 = *reinterpret_cast<const short8*>(Wp0 + k0);
    short8 b1 = *reinterpret_cast<const short8*>(Wp0 + (long)16 * K + k0);
    acc[0][0] = __builtin_amdgcn_mfma_f32_16x16x32_bf16(a0, b0, acc[0][0], 0, 0, 0);
    acc[0][1] = __builtin_amdgcn_mfma_f32_16x16x32_bf16(a0, b1, acc[0][1], 0, 0, 0);
    acc[1][0] = __builtin_amdgcn_mfma_f32_16x16x32_bf16(a1, b0, acc[1][0], 0, 0, 0);
    acc[1][1] = __builtin_amdgcn_mfma_f32_16x16x32_bf16(a1, b1, acc[1][1], 0, 0, 0);
  }
  #pragma unroll
  for (int mt = 0; mt < 2; ++mt)
  #pragma unroll
  for (int nt = 0; nt < 2; ++nt) {
    int n = bn0 + wn + 16 * nt + lr;
    float bv = bias ? bias[n] : 0.f;
    #pragma unroll
    for (int r = 0; r < 4; ++r) {
      int m = bm0 + wm + 16 * mt + (l >> 4) * 4 + r;
      float v = acc[mt][nt][r] + bv;
      if (ACT == 1) v = fmaxf(v, 0.f);
      if (RESID) v += bf2f(resid[(long)m * N + n]);
      long oi;
      if (PERM == 2) {
        int t = m & 511, b = m >> 9;
        oi = (long)((t * 16 + b) * 128 + (n & 127)) * 4 + (n >> 7);
      } else {
        oi = (long)bz * sO + (long)m * N + n;
      }
      if (OUT_BF16) ((u16*)outp)[oi] = f2bf(v);
      else          ((float*)outp)[oi] = v;
    }
  }
}

template<int ACT, bool OUT_BF16, int PERM, bool RESID>
__global__ __launch_bounds__(256) void gemm_bt(
    const u16* __restrict__ A, const u16* __restrict__ W,
    const float* __restrict__ bias, const u16* __restrict__ resid,
    void* __restrict__ outp, int M, int N, int K,
    long sA, long sW, long sO)
{
  gemm_bt_body<ACT, OUT_BF16, PERM, RESID>(A, W, bias, resid, outp, M, N, K,
                                           sA, sW, sO, blockIdx.x, blockIdx.y, blockIdx.z);
}

// ---------------- 8-wave BT-GEMM body (512 thr, 64x128 tile, bf16 out, bias) ----------------
__device__ __forceinline__ void gemm_bt_body8(
    const u16* __restrict__ A, const u16* __restrict__ W,
    const float* __restrict__ bias, u16* __restrict__ out,
    int N, int K, int bx, int by)
{
  const int bm0 = by * 64, bn0 = bx * 128;
  const int tid = threadIdx.x;
  const int l = tid & 63, wid = tid >> 6;
  const int wm = (wid >> 2) * 32, wn = (wid & 3) * 32;
  const int lr = l & 15, lk8 = (l >> 4) * 8;

  const f32x4 z4 = {0.f, 0.f, 0.f, 0.f};
  f32x4 acc[2][2] = {{z4, z4}, {z4, z4}};

  const u16* Ap0 = A + (long)(bm0 + wm + lr) * K + lk8;
  const u16* Wp0 = W + (long)(bn0 + wn + lr) * K + lk8;
  for (int k0 = 0; k0 < K; k0 += 32) {
    short8 a0 = *reinterpret_cast<const short8*>(Ap0 + k0);
    short8 a1 = *reinterpret_cast<const short8*>(Ap0 + (long)16 * K + k0);
    short8 b0 = *reinterpret_cast<const short8*>(Wp0 + k0);
    short8 b1 = *reinterpret_cast<const short8*>(Wp0 + (long)16 * K + k0);
    acc[0][0] = __builtin_amdgcn_mfma_f32_16x16x32_bf16(a0, b0, acc[0][0], 0, 0, 0);
    acc[0][1] = __builtin_amdgcn_mfma_f32_16x16x32_bf16(a0, b1, acc[0][1], 0, 0, 0);
    acc[1][0] = __builtin_amdgcn_mfma_f32_16x16x32_bf16(a1, b0, acc[1][0], 0, 0, 0);
    acc[1][1] = __builtin_amdgcn_mfma_f32_16x16x32_bf16(a1, b1, acc[1][1], 0, 0, 0);
  }
  #pragma unroll
  for (int mt = 0; mt < 2; ++mt)
  #pragma unroll
  for (int nt = 0; nt < 2; ++nt) {
    int n = bn0 + wn + 16 * nt + lr;
    float bv = bias[n];
    #pragma unroll
    for (int r = 0; r < 4; ++r) {
      int m = bm0 + wm + 16 * mt + (l >> 4) * 4 + r;
      out[(long)m * N + n] = f2bf(acc[mt][nt][r] + bv);
    }
  }
}

// ---------------- LSTM scan v7: the 426us structure, 2 batches/block (16 scan blocks) ----------------
// X: [t][b(16)][j(128)][gate(4)] f32 (includes biases).  Whh: [512][128] bf16 (plain).
// MFMA: A = h (rows=batches, 2 useful), B = Whh rows (z-cols). z exchanged via z_lds;
// gate phase: 1 quad/thread, waves 0-3 only (bq<2). Two barriers/step.
__device__ __forceinline__ void lstm_scan7_body(
    const float* __restrict__ X, const u16* __restrict__ Whh,
    u16* __restrict__ Hout, int dir, int bg)
{
  __shared__ __align__(16) u16 h_lds[16 * 136];   // rows 0..1 live, rest stay zero
  __shared__ float z_lds[2 * 516];

  const int tid = threadIdx.x;
  const int l = tid & 63, w = tid >> 6;
  const int lr = l & 15, lk = l >> 4;

  // Whh fragments (B operand): wave w covers z-cols [64w, 64w+64)
  short8 bfrag[4][4];
  #pragma unroll
  for (int nt = 0; nt < 4; ++nt)
    #pragma unroll
    for (int ks = 0; ks < 4; ++ks)
      bfrag[nt][ks] = *reinterpret_cast<const short8*>(
          Whh + (64 * w + 16 * nt + lr) * 128 + 32 * ks + 8 * lk);

  for (int i = tid; i < 16 * 136; i += 512) h_lds[i] = 0;

  const int j  = tid & 127;   // gate col within H
  const int bq = tid >> 7;    // local batch row 0..3 (only 0,1 active)
  float c = 0.f;
  float4 xA, xB, xC, xD;

  __syncthreads();

  auto loadX = [&](int t) -> float4 {
    int ta = dir ? (S_ - 1 - t) : t;
    return *reinterpret_cast<const float4*>(X + (size_t)((ta * 16 + bg + bq) * 128 + j) * 4);
  };
  if (bq < 2) { xA = loadX(0); xB = loadX(1); xC = loadX(2); }

  const f32x4 z4 = {0.f, 0.f, 0.f, 0.f};

  auto step = [&](int t, float4& xc, float4& xt, int tload) {
    // ---- phase A: z = h @ Whh^T (all 8 waves) ----
    short8 af[4];
    #pragma unroll
    for (int ks = 0; ks < 4; ++ks)
      af[ks] = *reinterpret_cast<const short8*>(h_lds + lr * 136 + 32 * ks + 8 * lk);
    f32x4 acc[4] = {z4, z4, z4, z4};
    #pragma unroll
    for (int nt = 0; nt < 4; ++nt)
      #pragma unroll
      for (int ks = 0; ks < 4; ++ks)
        acc[nt] = __builtin_amdgcn_mfma_f32_16x16x32_bf16(af[ks], bfrag[nt][ks], acc[nt], 0, 0, 0);
    if (lk == 0) {
      #pragma unroll
      for (int nt = 0; nt < 4; ++nt)
        #pragma unroll
        for (int r = 0; r < 2; ++r)
          z_lds[r * 516 + 64 * w + 16 * nt + lr] = acc[nt][r];
    }
    if (bq < 2 && tload < S_) xt = loadX(tload);   // deep prefetch, in flight across barriers
    asm volatile("s_waitcnt lgkmcnt(0)" ::: "memory");
    __builtin_amdgcn_s_barrier();
    // ---- phase B: gates (waves 0-3 only) ----
    if (bq < 2) {
      int ta = dir ? (S_ - 1 - t) : t;
      float zi = z_lds[bq * 516 + j      ] + xc.x;
      float zf = z_lds[bq * 516 + 128 + j] + xc.y;
      float zg = z_lds[bq * 516 + 256 + j] + xc.z;
      float zo = z_lds[bq * 516 + 384 + j] + xc.w;
      float si = __fdividef(1.f, 1.f + __expf(-zi));
      float sf = __fdividef(1.f, 1.f + __expf(-zf));
      float so = __fdividef(1.f, 1.f + __expf(-zo));
      float eg = __expf(2.f * zg);
      float tg = 1.f - __fdividef(2.f, eg + 1.f);
      c = sf * c + si * tg;
      float ec = __expf(2.f * c);
      float tc = 1.f - __fdividef(2.f, ec + 1.f);
      float hv = so * tc;
      u16 hb = f2bf(hv);
      h_lds[bq * 136 + j] = hb;
      Hout[((size_t)(bg + bq) * S_ + ta) * 256 + dir * 128 + j] = hb;
    }
    asm volatile("s_waitcnt lgkmcnt(0)" ::: "memory");
    __builtin_amdgcn_s_barrier();
  };

  for (int t = 0; t < S_; t += 4) {
    step(t,     xA, xD, t + 3);
    step(t + 1, xB, xA, t + 4);
    step(t + 2, xC, xB, t + 5);
    step(t + 3, xD, xC, t + 6);
  }
}

// ---------------- fused dispatch: blocks 0..15 = scan(dir,bat-pair), blocks 16.. = BT-GEMM ----------------
__global__ __launch_bounds__(512, 1) void scan_fused(
    const float* __restrict__ Xf, const float* __restrict__ Xb,
    const u16* __restrict__ Whhf, const u16* __restrict__ Whhb,
    u16* __restrict__ Hout,
    const u16* __restrict__ gA, const u16* __restrict__ gW,
    const float* __restrict__ gb, u16* __restrict__ gOut, int gK)
{
  if (blockIdx.x < 16) {
    int dir = blockIdx.x & 1, bg = (blockIdx.x >> 1) * 2;
    lstm_scan7_body(dir ? Xb : Xf, dir ? Whhb : Whhf, Hout, dir, bg);
  } else {
    int bi = blockIdx.x - 16;
    gemm_bt_body8(gA, gW, gb, gOut, 256, gK, bi & 1, bi >> 1);
  }
}

// ---------------- attention: sigmoid + diag/adj mask + row-normalize ----------------
__global__ __launch_bounds__(256) void attn_norm(
    const float* __restrict__ sc, const float* __restrict__ adj, u16* __restrict__ abf)
{
  int bz = blockIdx.y;
  int i = blockIdx.x * 4 + (threadIdx.x >> 6);
  int l = threadIdx.x & 63;
  const float* srow = sc  + ((long)bz * 512 + i) * 512;
  const float* arow = adj + ((long)bz * 512 + i) * 512;
  float av[8]; float sum = 0.f;
  #pragma unroll
  for (int k = 0; k < 8; ++k) {
    int jj = l + 64 * k;
    float sg = __fdividef(1.f, 1.f + __expf(-srow[jj]));
    float v = (jj == i) ? (sg + 1e-5f) : sg * arow[jj];
    av[k] = v; sum += v;
  }
  #pragma unroll
  for (int off = 32; off; off >>= 1) sum += __shfl_xor(sum, off);
  float r = __fdividef(1.f, sum);
  u16* orow = abf + ((long)bz * 512 + i) * 512;
  #pragma unroll
  for (int k = 0; k < 8; ++k) orow[l + 64 * k] = f2bf(av[k] * r);
}

// ---------------- transpose g: [B][512][256] -> [B][256][512] ----------------
__global__ __launch_bounds__(256) void transpose_g(const u16* __restrict__ in, u16* __restrict__ out)
{
  __shared__ u16 tile[32][33];
  int bz = blockIdx.z;
  int s0 = blockIdx.x * 32, d0 = blockIdx.y * 32;
  int tx = threadIdx.x & 31, ty = threadIdx.x >> 5;
  const u16* ip = in + (long)bz * 512 * 256;
  u16* op = out + (long)bz * 256 * 512;
  #pragma unroll
  for (int k = 0; k < 32; k += 8) tile[ty + k][tx] = ip[(long)(s0 + ty + k) * 256 + d0 + tx];
  __syncthreads();
  #pragma unroll
  for (int k = 0; k < 32; k += 8) op[(long)(d0 + ty + k) * 512 + s0 + tx] = tile[tx][ty + k];
}

// ---------------- mean over S of concat[lstm_out, g_final] -> d_out[32..] ----------------
__global__ __launch_bounds__(256) void mean_cat(
    const u16* __restrict__ lstm, const u16* __restrict__ gf, float* __restrict__ dout)
{
  int b = blockIdx.x;
  for (int cc = threadIdx.x; cc < 512; cc += 256) {
    const u16* src = (cc < 256) ? (lstm + (long)b * 512 * 256 + cc)
                                : (gf   + (long)b * 512 * 256 + (cc - 256));
    float s = 0.f;
    for (int t = 0; t < 512; ++t) s += bf2f(src[(long)t * 256]);
    dout[32 + b * 512 + cc] = s * (1.f / 512.f);
  }
}

// ---------------- head: fcA -> leaky -> fcB -> leaky -> fcC ----------------
__global__ __launch_bounds__(256) void head_kernel(
    const float* __restrict__ hidden,
    const float* __restrict__ fcA_W, const float* __restrict__ fcA_b,
    const float* __restrict__ fcB_W, const float* __restrict__ fcB_b,
    const float* __restrict__ fcC_W, const float* __restrict__ fcC_b,
    float* __restrict__ y)
{
  __shared__ float hb[16 * 512];
  __shared__ float ab[16 * 128];
  __shared__ float bb[16 * 32];
  int tid = threadIdx.x;
  for (int i = tid; i < 8192; i += 256) hb[i] = hidden[i];
  __syncthreads();
  for (int o = tid; o < 2048; o += 256) {
    int b = o >> 7, jj = o & 127;
    float acc = fcA_b[jj];
    const float* wrow = fcA_W + jj * 512;
    const float* hrow = hb + b * 512;
    for (int k = 0; k < 512; ++k) acc += hrow[k] * wrow[k];
    ab[o] = acc > 0.f ? acc : 0.1f * acc;
  }
  __syncthreads();
  for (int o = tid; o < 512; o += 256) {
    int b = o >> 5, jj = o & 31;
    float acc = fcB_b[jj];
    for (int k = 0; k < 128; ++k) acc += ab[b * 128 + k] * fcB_W[jj * 128 + k];
    bb[o] = acc > 0.f ? acc : 0.1f * acc;
  }
  __syncthreads();
  if (tid < 32) {
    int b = tid >> 1, jj = tid & 1;
    float acc = fcC_b[jj];
    for (int k = 0; k < 32; ++k) acc += bb[b * 32 + k] * fcC_W[jj * 32 + k];
    y[b * 2 + jj] = acc;
  }
}

extern "C" void kernel_launch(void* const* d_in, const int* in_sizes, int n_in,
                              void* d_out, int out_size, void* d_ws, size_t ws_size,
                              hipStream_t stream)
{
  const float* x       = (const float*)d_in[0];
  const float* adj     = (const float*)d_in[1];
  const float* l0f_Wih = (const float*)d_in[2];
  const float* l0f_Whh = (const float*)d_in[3];
  const float* l0f_bih = (const float*)d_in[4];
  const float* l0f_bhh = (const float*)d_in[5];
  const float* l0b_Wih = (const float*)d_in[6];
  const float* l0b_Whh = (const float*)d_in[7];
  const float* l0b_bih = (const float*)d_in[8];
  const float* l0b_bhh = (const float*)d_in[9];
  const float* l1f_Wih = (const float*)d_in[10];
  const float* l1f_Whh = (const float*)d_in[11];
  const float* l1f_bih = (const float*)d_in[12];
  const float* l1f_bhh = (const float*)d_in[13];
  const float* l1b_Wih = (const float*)d_in[14];
  const float* l1b_Whh = (const float*)d_in[15];
  const float* l1b_bih = (const float*)d_in[16];
  const float* l1b_bhh = (const float*)d_in[17];
  const float* fc1_W   = (const float*)d_in[18];
  const float* fc1_b   = (const float*)d_in[19];
  const float* wattn_W = (const float*)d_in[20];
  const float* wattn_b = (const float*)d_in[21];
  const float* lin0_W  = (const float*)d_in[22];
  const float* lin0_b  = (const float*)d_in[23];
  const float* lin1_W  = (const float*)d_in[24];
  const float* lin1_b  = (const float*)d_in[25];
  const float* linf_W  = (const float*)d_in[26];
  const float* linf_b  = (const float*)d_in[27];
  const float* fcA_W   = (const float*)d_in[28];
  const float* fcA_b   = (const float*)d_in[29];
  const float* fcB_W   = (const float*)d_in[30];
  const float* fcB_b   = (const float*)d_in[31];
  const float* fcC_W   = (const float*)d_in[32];
  const float* fcC_b   = (const float*)d_in[33];

  char* wp = (char*)d_ws;
  auto alloc = [&](size_t n) -> void* { void* p = wp; wp += (n + 255) & ~(size_t)255; return p; };

  u16* x_bf     = (u16*)alloc((size_t)B_ * S_ * D_ * 2);
  u16* w0f_ih   = (u16*)alloc((size_t)512 * 1024 * 2);
  u16* w0b_ih   = (u16*)alloc((size_t)512 * 1024 * 2);
  u16* w1f_ih   = (u16*)alloc((size_t)512 * 256 * 2);
  u16* w1b_ih   = (u16*)alloc((size_t)512 * 256 * 2);
  u16* w0f_hh   = (u16*)alloc((size_t)512 * 128 * 2);
  u16* w0b_hh   = (u16*)alloc((size_t)512 * 128 * 2);
  u16* w1f_hh   = (u16*)alloc((size_t)512 * 128 * 2);
  u16* w1b_hh   = (u16*)alloc((size_t)512 * 128 * 2);
  u16* wfc1     = (u16*)alloc((size_t)256 * 1024 * 2);
  u16* wattn_bf = (u16*)alloc((size_t)4 * 256 * 256 * 2);
  u16* wlin0_bf = (u16*)alloc((size_t)4 * 256 * 256 * 2);
  u16* wlin1_bf = (u16*)alloc((size_t)4 * 256 * 256 * 2);
  u16* wlinf_bf = (u16*)alloc((size_t)256 * 256 * 2);
  float* bias4  = (float*)alloc((size_t)2048 * 4);
  float* X0f    = (float*)alloc((size_t)S_ * 16 * 512 * 4);
  float* X0b    = (float*)alloc((size_t)S_ * 16 * 512 * 4);
  u16* h0       = (u16*)alloc((size_t)B_ * S_ * 256 * 2);
  u16* lstm_out = (u16*)alloc((size_t)B_ * S_ * 256 * 2);
  u16* gA       = (u16*)alloc((size_t)B_ * S_ * 256 * 2);
  u16* gB       = (u16*)alloc((size_t)B_ * S_ * 256 * 2);
  u16* qb       = (u16*)alloc((size_t)B_ * S_ * 256 * 2);
  u16* gT       = (u16*)alloc((size_t)B_ * S_ * 256 * 2);
  u16* t1       = (u16*)alloc((size_t)B_ * S_ * 256 * 2);
  u16* t2       = (u16*)alloc((size_t)B_ * S_ * 256 * 2);
  float* sc     = (float*)alloc((size_t)B_ * S_ * S_ * 4);
  u16* abf      = (u16*)alloc((size_t)B_ * S_ * S_ * 2);

  // ---- conversions (14 segments, exactly fills CvtSegs) ----
  CvtSegs cs;
  int nb = 0, si = 0;
  auto seg = [&](const float* s, u16* d, int n) {
    cs.src[si] = (const float4*)s; cs.dst[si] = (short4*)d;
    cs.blk0[si] = nb; nb += (n / 4 + 255) / 256; ++si;
  };
  seg(x, x_bf, B_ * S_ * D_);
  seg(l0f_Wih, w0f_ih, 512 * 1024);
  seg(l0b_Wih, w0b_ih, 512 * 1024);
  seg(l1f_Wih, w1f_ih, 512 * 256);
  seg(l1b_Wih, w1b_ih, 512 * 256);
  seg(l0f_Whh, w0f_hh, 512 * 128);
  seg(l0b_Whh, w0b_hh, 512 * 128);
  seg(l1f_Whh, w1f_hh, 512 * 128);
  seg(l1b_Whh, w1b_hh, 512 * 128);
  seg(fc1_W, wfc1, 256 * 1024);
  seg(wattn_W, wattn_bf, 4 * 256 * 256);
  seg(lin0_W, wlin0_bf, 4 * 256 * 256);
  seg(lin1_W, wlin1_bf, 4 * 256 * 256);
  seg(linf_W, wlinf_bf, 256 * 256);
  for (int k = si; k <= 14; ++k) cs.blk0[k] = nb;
  cvt_multi<<<nb, 256, 0, stream>>>(cs);
  bias_prep<<<8, 256, 0, stream>>>(l0f_bih, l0f_bhh, l0b_bih, l0b_bhh,
                                   l1f_bih, l1f_bhh, l1b_bih, l1b_bhh, bias4);

  // ---- LSTM layer 0: input projections (PERM2 -> f32 X), then scan (+fc1 GEMM fused) ----
  gemm_bt<0, false, 2, false><<<dim3(8, 128, 1), 256, 0, stream>>>(
      x_bf, w0f_ih, bias4 + 0, nullptr, X0f, 8192, 512, 1024, 0, 0, 0);
  gemm_bt<0, false, 2, false><<<dim3(8, 128, 1), 256, 0, stream>>>(
      x_bf, w0b_ih, bias4 + 512, nullptr, X0b, 8192, 512, 1024, 0, 0, 0);
  scan_fused<<<16 + 256, 512, 0, stream>>>(X0f, X0b, w0f_hh, w0b_hh, h0,
                                           x_bf, wfc1, fc1_b, gA, 1024);
  // ---- LSTM layer 1 (+ GAT layer-0 wattn GEMM fused) ----
  gemm_bt<0, false, 2, false><<<dim3(8, 128, 1), 256, 0, stream>>>(
      h0, w1f_ih, bias4 + 1024, nullptr, X0f, 8192, 512, 256, 0, 0, 0);
  gemm_bt<0, false, 2, false><<<dim3(8, 128, 1), 256, 0, stream>>>(
      h0, w1b_ih, bias4 + 1536, nullptr, X0b, 8192, 512, 256, 0, 0, 0);
  scan_fused<<<16 + 256, 512, 0, stream>>>(X0f, X0b, w1f_hh, w1b_hh, lstm_out,
                                           gA, wattn_bf, wattn_b, qb, 256);

  // ---- GAT ----
  u16* gcur = gA; u16* gnext = gB;
  for (int lyr = 0; lyr < 4; ++lyr) {
    if (lyr > 0)
      gemm_bt<0, true, 0, false><<<dim3(4, 128, 1), 256, 0, stream>>>(
          gcur, wattn_bf + lyr * 65536, wattn_b + lyr * 256, nullptr, qb, 8192, 256, 256, 0, 0, 0);
    gemm_bt<0, false, 0, false><<<dim3(8, 8, 16), 256, 0, stream>>>(
        qb, gcur, nullptr, nullptr, sc, 512, 512, 256, 131072, 131072, 262144);
    attn_norm<<<dim3(128, 16), 256, 0, stream>>>(sc, adj, abf);
    transpose_g<<<dim3(16, 8, 16), 256, 0, stream>>>(gcur, gT);
    gemm_bt<0, true, 0, false><<<dim3(4, 8, 16), 256, 0, stream>>>(
        abf, gT, nullptr, nullptr, t1, 512, 256, 512, 262144, 131072, 131072);
    gemm_bt<1, true, 0, false><<<dim3(4, 128, 1), 256, 0, stream>>>(
        t1, wlin0_bf + lyr * 65536, lin0_b + lyr * 256, nullptr, t2, 8192, 256, 256, 0, 0, 0);
    gemm_bt<1, true, 0, true><<<dim3(4, 128, 1), 256, 0, stream>>>(
        t2, wlin1_bf + lyr * 65536, lin1_b + lyr * 256, gcur, gnext, 8192, 256, 256, 0, 0, 0);
    u16* tmp = gcur; gcur = gnext; gnext = tmp;
  }
  gemm_bt<0, true, 0, false><<<dim3(4, 128, 1), 256, 0, stream>>>(
      gcur, wlinf_bf, linf_b, nullptr, t2, 8192, 256, 256, 0, 0, 0);

  // ---- pool + head ----
  mean_cat<<<16, 256, 0, stream>>>(lstm_out, t2, (float*)d_out);
  head_kernel<<<1, 256, 0, stream>>>((const float*)d_out + 32,
                                     fcA_W, fcA_b, fcB_W, fcB_b, fcC_W, fcC_b,
                                     (float*)d_out);
}

// Round 10
// 1231.480 us; speedup vs baseline: 1.8850x; 1.1040x over previous
//
#include <hip/hip_runtime.h>
#include <stdint.h>

#define B_ 16
#define S_ 512
#define D_ 1024
#define H4 512
#define G_ 256

typedef unsigned short u16;
using short8 = __attribute__((ext_vector_type(8))) short;
using f32x4  = __attribute__((ext_vector_type(4))) float;

__device__ __forceinline__ u16 f2bf(float f){
  unsigned int u = __float_as_uint(f);
  u += 0x7fffu + ((u >> 16) & 1u);
  return (u16)(u >> 16);
}
__device__ __forceinline__ float bf2f(u16 h){
  return __uint_as_float(((unsigned int)h) << 16);
}

// ---------------- single-dispatch f32 -> bf16 convert over all segments ----------------
struct CvtSegs {
  const float4* src[14];
  short4* dst[14];
  int blk0[15];
};
__global__ __launch_bounds__(256) void cvt_multi(CvtSegs cs){
  int blk = blockIdx.x;
  int s = 0;
  #pragma unroll
  for (int k = 0; k < 14; ++k) if (cs.blk0[k + 1] <= blk) s = k + 1;
  int i = (blk - cs.blk0[s]) * 256 + threadIdx.x;
  float4 v = cs.src[s][i];
  short4 o;
  o.x = (short)f2bf(v.x); o.y = (short)f2bf(v.y);
  o.z = (short)f2bf(v.z); o.w = (short)f2bf(v.w);
  cs.dst[s][i] = o;
}

// ---------------- LSTM bias sums (bih+bhh) ----------------
__global__ __launch_bounds__(256) void bias_prep(const float* a,const float* b,const float* c,const float* d,
                                                 const float* e,const float* f,const float* g,const float* h,
                                                 float* out){
  int i = blockIdx.x * 256 + threadIdx.x;
  if (i >= 2048) return;
  int p = i >> 9, k = i & 511;
  const float* x1 = (p==0)?a:(p==1)?c:(p==2)?e:g;
  const float* x2 = (p==0)?b:(p==1)?d:(p==2)?f:h;
  out[i] = x1[k] + x2[k];
}

// ---------------- MFMA BT-GEMM body (256 thr, 64x64 tile) ----------------
// EPI: 0=none, 1=relu, 2=score-mask (sigmoid+adj+eye, ex=adj), 3=row-scale (ex=rinv)
// PERM: 0 = row-major out, 2 = gate-interleaved X layout
template<int EPI, bool OUT_BF16, int PERM, bool RESID>
__device__ __forceinline__ void gemm_bt_body(
    const u16* __restrict__ A, const u16* __restrict__ W,
    const float* __restrict__ bias, const u16* __restrict__ resid,
    const float* __restrict__ ex,
    void* __restrict__ outp, int M, int N, int K,
    long sA, long sW, long sO, int bx, int by, int bz)
{
  const u16* Ab = A + (long)bz * sA;
  const u16* Wb = W + (long)bz * sW;
  const int bm0 = by * 64, bn0 = bx * 64;
  const int tid = threadIdx.x;
  const int l = tid & 63, wid = tid >> 6;
  const int wm = (wid >> 1) * 32, wn = (wid & 1) * 32;
  const int lr = l & 15, lk8 = (l >> 4) * 8;

  const f32x4 z4 = {0.f, 0.f, 0.f, 0.f};
  f32x4 acc[2][2] = {{z4, z4}, {z4, z4}};

  const u16* Ap0 = Ab + (long)(bm0 + wm + lr) * K + lk8;
  const u16* Wp0 = Wb + (long)(bn0 + wn + lr) * K + lk8;
  for (int k0 = 0; k0 < K; k0 += 32) {
    short8 a0 = *reinterpret_cast<const short8*>(Ap0 + k0);
    short8 a1 = *reinterpret_cast<const short8*>(Ap0 + (long)16 * K + k0);
    short8 b0 = *reinterpret_cast<const short8*>(Wp0 + k0);
    short8 b1 = *reinterpret_cast<const short8*>(Wp0 + (long)16 * K + k0);
    acc[0][0] = __builtin_amdgcn_mfma_f32_16x16x32_bf16(a0, b0, acc[0][0], 0, 0, 0);
    acc[0][1] = __builtin_amdgcn_mfma_f32_16x16x32_bf16(a0, b1, acc[0][1], 0, 0, 0);
    acc[1][0] = __builtin_amdgcn_mfma_f32_16x16x32_bf16(a1, b0, acc[1][0], 0, 0, 0);
    acc[1][1] = __builtin_amdgcn_mfma_f32_16x16x32_bf16(a1, b1, acc[1][1], 0, 0, 0);
  }
  #pragma unroll
  for (int mt = 0; mt < 2; ++mt)
  #pragma unroll
  for (int nt = 0; nt < 2; ++nt) {
    int n = bn0 + wn + 16 * nt + lr;
    float bv = bias ? bias[n] : 0.f;
    #pragma unroll
    for (int r = 0; r < 4; ++r) {
      int m = bm0 + wm + 16 * mt + (l >> 4) * 4 + r;
      float v = acc[mt][nt][r] + bv;
      if (EPI == 1) v = fmaxf(v, 0.f);
      if (EPI == 2) {
        float sg = __fdividef(1.f, 1.f + __expf(-v));
        v = (n == m) ? (sg + 1e-5f) : sg * ex[((long)bz * 512 + m) * 512 + n];
      }
      if (EPI == 3) v *= ex[(long)bz * 512 + m];
      if (RESID) v += bf2f(resid[(long)m * N + n]);
      long oi;
      if (PERM == 2) {
        int t = m & 511, b = m >> 9;
        oi = (long)((t * 16 + b) * 128 + (n & 127)) * 4 + (n >> 7);
      } else {
        oi = (long)bz * sO + (long)m * N + n;
      }
      if (OUT_BF16) ((u16*)outp)[oi] = f2bf(v);
      else          ((float*)outp)[oi] = v;
    }
  }
}

template<int EPI, bool OUT_BF16, int PERM, bool RESID>
__global__ __launch_bounds__(256) void gemm_bt(
    const u16* __restrict__ A, const u16* __restrict__ W,
    const float* __restrict__ bias, const u16* __restrict__ resid,
    const float* __restrict__ ex,
    void* __restrict__ outp, int M, int N, int K,
    long sA, long sW, long sO)
{
  gemm_bt_body<EPI, OUT_BF16, PERM, RESID>(A, W, bias, resid, ex, outp, M, N, K,
                                           sA, sW, sO, blockIdx.x, blockIdx.y, blockIdx.z);
}

// ---------------- fused f/b input projections (PERM2, f32 out) ----------------
__global__ __launch_bounds__(256) void proj2(
    const u16* __restrict__ A, const u16* __restrict__ W0, const u16* __restrict__ W1,
    const float* __restrict__ bias, float* __restrict__ O0, float* __restrict__ O1, int K)
{
  int z = blockIdx.z;
  gemm_bt_body<0, false, 2, false>(A, z ? W1 : W0, bias + z * 512, nullptr, nullptr,
                                   z ? O1 : O0, 8192, 512, K, 0, 0, 0,
                                   blockIdx.x, blockIdx.y, 0);
}

// ---------------- 8-wave BT-GEMM body (512 thr, 64x128 tile, bf16 out, bias) ----------------
__device__ __forceinline__ void gemm_bt_body8(
    const u16* __restrict__ A, const u16* __restrict__ W,
    const float* __restrict__ bias, u16* __restrict__ out,
    int N, int K, int bx, int by)
{
  const int bm0 = by * 64, bn0 = bx * 128;
  const int tid = threadIdx.x;
  const int l = tid & 63, wid = tid >> 6;
  const int wm = (wid >> 2) * 32, wn = (wid & 3) * 32;
  const int lr = l & 15, lk8 = (l >> 4) * 8;

  const f32x4 z4 = {0.f, 0.f, 0.f, 0.f};
  f32x4 acc[2][2] = {{z4, z4}, {z4, z4}};

  const u16* Ap0 = A + (long)(bm0 + wm + lr) * K + lk8;
  const u16* Wp0 = W + (long)(bn0 + wn + lr) * K + lk8;
  for (int k0 = 0; k0 < K; k0 += 32) {
    short8 a0 = *reinterpret_cast<const short8*>(Ap0 + k0);
    short8 a1 = *reinterpret_cast<const short8*>(Ap0 + (long)16 * K + k0);
    short8 b0 = *reinterpret_cast<const short8*>(Wp0 + k0);
    short8 b1 = *reinterpret_cast<const short8*>(Wp0 + (long)16 * K + k0);
    acc[0][0] = __builtin_amdgcn_mfma_f32_16x16x32_bf16(a0, b0, acc[0][0], 0, 0, 0);
    acc[0][1] = __builtin_amdgcn_mfma_f32_16x16x32_bf16(a0, b1, acc[0][1], 0, 0, 0);
    acc[1][0] = __builtin_amdgcn_mfma_f32_16x16x32_bf16(a1, b0, acc[1][0], 0, 0, 0);
    acc[1][1] = __builtin_amdgcn_mfma_f32_16x16x32_bf16(a1, b1, acc[1][1], 0, 0, 0);
  }
  #pragma unroll
  for (int mt = 0; mt < 2; ++mt)
  #pragma unroll
  for (int nt = 0; nt < 2; ++nt) {
    int n = bn0 + wn + 16 * nt + lr;
    float bv = bias[n];
    #pragma unroll
    for (int r = 0; r < 4; ++r) {
      int m = bm0 + wm + 16 * mt + (l >> 4) * 4 + r;
      out[(long)m * N + n] = f2bf(acc[mt][nt][r] + bv);
    }
  }
}

// ---------------- LSTM scan v8: 32 blocks (dir x batch), in-register z quads ----------------
// X: [t][b(16)][j(128)][gate(4)] f32.  Whh: [512][128] bf16 plain (rows: gate*128+j).
// Wave w's 4 nt tiles = z-cols {g*128+16w .. +16} for g=0..3  ->  lane l<16 holds the full
// (zi,zf,zg,zo) quad for j=16w+l in acc[0..3][0]. No z exchange; ONE barrier/step.
// h double-buffered in LDS (rows 1..15 zero; all lanes supply A k-slices of row lr).
__device__ __forceinline__ void lstm_scan8_body(
    const float* __restrict__ X, const u16* __restrict__ Whh,
    u16* __restrict__ Hout, int dir, int bat)
{
  __shared__ __align__(16) u16 hbuf[2][16][136];   // [parity][A-row][j] ~8.5KB

  const int tid = threadIdx.x;
  const int l = tid & 63, w = tid >> 6;
  const int lr = l & 15, lk = l >> 4;

  // B fragments: gate g tile = Whh rows [g*128 + 16w, +16)
  short8 bfrag[4][4];
  #pragma unroll
  for (int g = 0; g < 4; ++g)
    #pragma unroll
    for (int ks = 0; ks < 4; ++ks)
      bfrag[g][ks] = *reinterpret_cast<const short8*>(
          Whh + (g * 128 + 16 * w + lr) * 128 + 32 * ks + 8 * lk);

  for (int i = tid; i < 2 * 16 * 136; i += 512) ((u16*)hbuf)[i] = 0;

  float c = 0.f;
  const f32x4 z4 = {0.f, 0.f, 0.f, 0.f};

  auto ldX = [&](int t) -> float4 {
    int ta = dir ? (S_ - 1 - t) : t;
    return *reinterpret_cast<const float4*>(X + (size_t)((ta * 16 + bat) * 128 + 16 * w + lr) * 4);
  };
  float4 xA, xB, xC, xD;
  if (lk == 0) { xA = ldX(0); xB = ldX(1); xC = ldX(2); }
  __syncthreads();

  auto step = [&](int t, float4& xc, float4& xt, int tload) {
    const int p = t & 1;
    short8 af[4];
    #pragma unroll
    for (int ks = 0; ks < 4; ++ks)
      af[ks] = *reinterpret_cast<const short8*>(&hbuf[p][lr][32 * ks + 8 * lk]);
    f32x4 acc[4] = {z4, z4, z4, z4};
    #pragma unroll
    for (int g = 0; g < 4; ++g)
      #pragma unroll
      for (int ks = 0; ks < 4; ++ks)
        acc[g] = __builtin_amdgcn_mfma_f32_16x16x32_bf16(af[ks], bfrag[g][ks], acc[g], 0, 0, 0);
    if (lk == 0) {
      if (tload < S_) xt = ldX(tload);   // deep prefetch
      float zi = acc[0][0] + xc.x;
      float zf = acc[1][0] + xc.y;
      float zg = acc[2][0] + xc.z;
      float zo = acc[3][0] + xc.w;
      float si = __fdividef(1.f, 1.f + __expf(-zi));
      float sf = __fdividef(1.f, 1.f + __expf(-zf));
      float so = __fdividef(1.f, 1.f + __expf(-zo));
      float eg = __expf(2.f * zg);
      float tg = 1.f - __fdividef(2.f, eg + 1.f);
      c = sf * c + si * tg;
      float ec = __expf(2.f * c);
      float tc = 1.f - __fdividef(2.f, ec + 1.f);
      u16 hb = f2bf(so * tc);
      int ta = dir ? (S_ - 1 - t) : t;
      hbuf[p ^ 1][0][16 * w + lr] = hb;
      Hout[((size_t)bat * S_ + ta) * 256 + dir * 128 + 16 * w + lr] = hb;
    }
    asm volatile("s_waitcnt lgkmcnt(0)" ::: "memory");
    __builtin_amdgcn_s_barrier();
  };

  for (int t = 0; t < S_; t += 4) {
    step(t,     xA, xD, t + 3);
    step(t + 1, xB, xA, t + 4);
    step(t + 2, xC, xB, t + 5);
    step(t + 3, xD, xC, t + 6);
  }
}

// ---------------- fused dispatch: blocks 0..31 = scan(dir,bat), blocks 32.. = BT-GEMM ----------------
__global__ __launch_bounds__(512, 1) void scan_fused(
    const float* __restrict__ Xf, const float* __restrict__ Xb,
    const u16* __restrict__ Whhf, const u16* __restrict__ Whhb,
    u16* __restrict__ Hout,
    const u16* __restrict__ gA, const u16* __restrict__ gW,
    const float* __restrict__ gb, u16* __restrict__ gOut, int gK)
{
  if (blockIdx.x < 32) {
    int dir = blockIdx.x & 1, bat = blockIdx.x >> 1;
    lstm_scan8_body(dir ? Xb : Xf, dir ? Whhb : Whhf, Hout, dir, bat);
  } else {
    int bi = blockIdx.x - 32;
    gemm_bt_body8(gA, gW, gb, gOut, 256, gK, bi & 1, bi >> 1);
  }
}

// ---------------- transpose body + kernels ----------------
__device__ __forceinline__ void transpose_body(const u16* __restrict__ in, u16* __restrict__ out,
                                               int bz, int s0, int d0)
{
  __shared__ u16 tile[32][33];
  int tx = threadIdx.x & 31, ty = threadIdx.x >> 5;
  const u16* ip = in + (long)bz * 512 * 256;
  u16* op = out + (long)bz * 256 * 512;
  #pragma unroll
  for (int k = 0; k < 32; k += 8) tile[ty + k][tx] = ip[(long)(s0 + ty + k) * 256 + d0 + tx];
  __syncthreads();
  #pragma unroll
  for (int k = 0; k < 32; k += 8) op[(long)(d0 + ty + k) * 512 + s0 + tx] = tile[tx][ty + k];
}

__global__ __launch_bounds__(256) void transpose_g(const u16* __restrict__ in, u16* __restrict__ out)
{
  transpose_body(in, out, blockIdx.z, blockIdx.x * 32, blockIdx.y * 32);
}

// wattn GEMM (512 blocks) || transpose (2048 blocks), both read gcur
__global__ __launch_bounds__(256) void wattn_trans(
    const u16* __restrict__ gcur, const u16* __restrict__ wW, const float* __restrict__ wb,
    u16* __restrict__ qb, u16* __restrict__ gT)
{
  if (blockIdx.x < 512) {
    int b = blockIdx.x;
    gemm_bt_body<0, true, 0, false>(gcur, wW, wb, nullptr, nullptr, qb,
                                    8192, 256, 256, 0, 0, 0, b & 3, b >> 2, 0);
  } else {
    int b = blockIdx.x - 512;
    int bz = b >> 7, rem = b & 127;
    transpose_body(gcur, gT, bz, (rem & 15) * 32, (rem >> 4) * 32);
  }
}

// ---------------- row-sum reciprocal of masked scores ----------------
__global__ __launch_bounds__(256) void rowsum_inv(const u16* __restrict__ abf, float* __restrict__ rinv)
{
  int bz = blockIdx.y;
  int row = blockIdx.x * 4 + (threadIdx.x >> 6);
  int l = threadIdx.x & 63;
  short8 v = *reinterpret_cast<const short8*>(abf + ((size_t)bz * 512 + row) * 512 + l * 8);
  float s = 0.f;
  #pragma unroll
  for (int k = 0; k < 8; ++k) s += bf2f((u16)v[k]);
  #pragma unroll
  for (int off = 32; off; off >>= 1) s += __shfl_xor(s, off);
  if (l == 0) rinv[bz * 512 + row] = __fdividef(1.f, s);
}

// ---------------- mean over S of concat[lstm_out, g_final] -> d_out[32..] ----------------
__global__ __launch_bounds__(256) void mean_cat(
    const u16* __restrict__ lstm, const u16* __restrict__ gf, float* __restrict__ dout)
{
  int b = blockIdx.x;
  for (int cc = threadIdx.x; cc < 512; cc += 256) {
    const u16* src = (cc < 256) ? (lstm + (long)b * 512 * 256 + cc)
                                : (gf   + (long)b * 512 * 256 + (cc - 256));
    float s = 0.f;
    for (int t = 0; t < 512; ++t) s += bf2f(src[(long)t * 256]);
    dout[32 + b * 512 + cc] = s * (1.f / 512.f);
  }
}

// ---------------- head: fcA -> leaky -> fcB -> leaky -> fcC ----------------
__global__ __launch_bounds__(256) void head_kernel(
    const float* __restrict__ hidden,
    const float* __restrict__ fcA_W, const float* __restrict__ fcA_b,
    const float* __restrict__ fcB_W, const float* __restrict__ fcB_b,
    const float* __restrict__ fcC_W, const float* __restrict__ fcC_b,
    float* __restrict__ y)
{
  __shared__ float hb[16 * 512];
  __shared__ float ab[16 * 128];
  __shared__ float bb[16 * 32];
  int tid = threadIdx.x;
  for (int i = tid; i < 8192; i += 256) hb[i] = hidden[i];
  __syncthreads();
  for (int o = tid; o < 2048; o += 256) {
    int b = o >> 7, jj = o & 127;
    float acc = fcA_b[jj];
    const float* wrow = fcA_W + jj * 512;
    const float* hrow = hb + b * 512;
    for (int k = 0; k < 512; ++k) acc += hrow[k] * wrow[k];
    ab[o] = acc > 0.f ? acc : 0.1f * acc;
  }
  __syncthreads();
  for (int o = tid; o < 512; o += 256) {
    int b = o >> 5, jj = o & 31;
    float acc = fcB_b[jj];
    for (int k = 0; k < 128; ++k) acc += ab[b * 128 + k] * fcB_W[jj * 128 + k];
    bb[o] = acc > 0.f ? acc : 0.1f * acc;
  }
  __syncthreads();
  if (tid < 32) {
    int b = tid >> 1, jj = tid & 1;
    float acc = fcC_b[jj];
    for (int k = 0; k < 32; ++k) acc += bb[b * 32 + k] * fcC_W[jj * 32 + k];
    y[b * 2 + jj] = acc;
  }
}

extern "C" void kernel_launch(void* const* d_in, const int* in_sizes, int n_in,
                              void* d_out, int out_size, void* d_ws, size_t ws_size,
                              hipStream_t stream)
{
  const float* x       = (const float*)d_in[0];
  const float* adj     = (const float*)d_in[1];
  const float* l0f_Wih = (const float*)d_in[2];
  const float* l0f_Whh = (const float*)d_in[3];
  const float* l0f_bih = (const float*)d_in[4];
  const float* l0f_bhh = (const float*)d_in[5];
  const float* l0b_Wih = (const float*)d_in[6];
  const float* l0b_Whh = (const float*)d_in[7];
  const float* l0b_bih = (const float*)d_in[8];
  const float* l0b_bhh = (const float*)d_in[9];
  const float* l1f_Wih = (const float*)d_in[10];
  const float* l1f_Whh = (const float*)d_in[11];
  const float* l1f_bih = (const float*)d_in[12];
  const float* l1f_bhh = (const float*)d_in[13];
  const float* l1b_Wih = (const float*)d_in[14];
  const float* l1b_Whh = (const float*)d_in[15];
  const float* l1b_bih = (const float*)d_in[16];
  const float* l1b_bhh = (const float*)d_in[17];
  const float* fc1_W   = (const float*)d_in[18];
  const float* fc1_b   = (const float*)d_in[19];
  const float* wattn_W = (const float*)d_in[20];
  const float* wattn_b = (const float*)d_in[21];
  const float* lin0_W  = (const float*)d_in[22];
  const float* lin0_b  = (const float*)d_in[23];
  const float* lin1_W  = (const float*)d_in[24];
  const float* lin1_b  = (const float*)d_in[25];
  const float* linf_W  = (const float*)d_in[26];
  const float* linf_b  = (const float*)d_in[27];
  const float* fcA_W   = (const float*)d_in[28];
  const float* fcA_b   = (const float*)d_in[29];
  const float* fcB_W   = (const float*)d_in[30];
  const float* fcB_b   = (const float*)d_in[31];
  const float* fcC_W   = (const float*)d_in[32];
  const float* fcC_b   = (const float*)d_in[33];

  char* wp = (char*)d_ws;
  auto alloc = [&](size_t n) -> void* { void* p = wp; wp += (n + 255) & ~(size_t)255; return p; };

  u16* x_bf     = (u16*)alloc((size_t)B_ * S_ * D_ * 2);
  u16* w0f_ih   = (u16*)alloc((size_t)512 * 1024 * 2);
  u16* w0b_ih   = (u16*)alloc((size_t)512 * 1024 * 2);
  u16* w1f_ih   = (u16*)alloc((size_t)512 * 256 * 2);
  u16* w1b_ih   = (u16*)alloc((size_t)512 * 256 * 2);
  u16* w0f_hh   = (u16*)alloc((size_t)512 * 128 * 2);
  u16* w0b_hh   = (u16*)alloc((size_t)512 * 128 * 2);
  u16* w1f_hh   = (u16*)alloc((size_t)512 * 128 * 2);
  u16* w1b_hh   = (u16*)alloc((size_t)512 * 128 * 2);
  u16* wfc1     = (u16*)alloc((size_t)256 * 1024 * 2);
  u16* wattn_bf = (u16*)alloc((size_t)4 * 256 * 256 * 2);
  u16* wlin0_bf = (u16*)alloc((size_t)4 * 256 * 256 * 2);
  u16* wlin1_bf = (u16*)alloc((size_t)4 * 256 * 256 * 2);
  u16* wlinf_bf = (u16*)alloc((size_t)256 * 256 * 2);
  float* bias4  = (float*)alloc((size_t)2048 * 4);
  float* X0f    = (float*)alloc((size_t)S_ * 16 * 512 * 4);
  float* X0b    = (float*)alloc((size_t)S_ * 16 * 512 * 4);
  u16* h0       = (u16*)alloc((size_t)B_ * S_ * 256 * 2);
  u16* lstm_out = (u16*)alloc((size_t)B_ * S_ * 256 * 2);
  u16* gA       = (u16*)alloc((size_t)B_ * S_ * 256 * 2);
  u16* gB       = (u16*)alloc((size_t)B_ * S_ * 256 * 2);
  u16* qb       = (u16*)alloc((size_t)B_ * S_ * 256 * 2);
  u16* gT       = (u16*)alloc((size_t)B_ * S_ * 256 * 2);
  u16* t1       = (u16*)alloc((size_t)B_ * S_ * 256 * 2);
  u16* t2       = (u16*)alloc((size_t)B_ * S_ * 256 * 2);
  u16* abf      = (u16*)alloc((size_t)B_ * S_ * S_ * 2);
  float* rinv   = (float*)alloc((size_t)B_ * S_ * 4);

  // ---- conversions (14 segments) ----
  CvtSegs cs;
  int nb = 0, si = 0;
  auto seg = [&](const float* s, u16* d, int n) {
    cs.src[si] = (const float4*)s; cs.dst[si] = (short4*)d;
    cs.blk0[si] = nb; nb += (n / 4 + 255) / 256; ++si;
  };
  seg(x, x_bf, B_ * S_ * D_);
  seg(l0f_Wih, w0f_ih, 512 * 1024);
  seg(l0b_Wih, w0b_ih, 512 * 1024);
  seg(l1f_Wih, w1f_ih, 512 * 256);
  seg(l1b_Wih, w1b_ih, 512 * 256);
  seg(l0f_Whh, w0f_hh, 512 * 128);
  seg(l0b_Whh, w0b_hh, 512 * 128);
  seg(l1f_Whh, w1f_hh, 512 * 128);
  seg(l1b_Whh, w1b_hh, 512 * 128);
  seg(fc1_W, wfc1, 256 * 1024);
  seg(wattn_W, wattn_bf, 4 * 256 * 256);
  seg(lin0_W, wlin0_bf, 4 * 256 * 256);
  seg(lin1_W, wlin1_bf, 4 * 256 * 256);
  seg(linf_W, wlinf_bf, 256 * 256);
  for (int k = si; k <= 14; ++k) cs.blk0[k] = nb;
  cvt_multi<<<nb, 256, 0, stream>>>(cs);
  bias_prep<<<8, 256, 0, stream>>>(l0f_bih, l0f_bhh, l0b_bih, l0b_bhh,
                                   l1f_bih, l1f_bhh, l1b_bih, l1b_bhh, bias4);

  // ---- LSTM layer 0: fused f/b projections, then scan (+fc1 GEMM fused) ----
  proj2<<<dim3(8, 128, 2), 256, 0, stream>>>(x_bf, w0f_ih, w0b_ih, bias4, X0f, X0b, 1024);
  scan_fused<<<32 + 256, 512, 0, stream>>>(X0f, X0b, w0f_hh, w0b_hh, h0,
                                           x_bf, wfc1, fc1_b, gA, 1024);
  // ---- LSTM layer 1 (+ GAT layer-0 wattn GEMM fused) ----
  proj2<<<dim3(8, 128, 2), 256, 0, stream>>>(h0, w1f_ih, w1b_ih, bias4 + 1024, X0f, X0b, 256);
  scan_fused<<<32 + 256, 512, 0, stream>>>(X0f, X0b, w1f_hh, w1b_hh, lstm_out,
                                           gA, wattn_bf, wattn_b, qb, 256);

  // ---- GAT ----
  u16* gcur = gA; u16* gnext = gB;
  for (int lyr = 0; lyr < 4; ++lyr) {
    if (lyr == 0)
      transpose_g<<<dim3(16, 8, 16), 256, 0, stream>>>(gcur, gT);
    else
      wattn_trans<<<512 + 2048, 256, 0, stream>>>(gcur, wattn_bf + lyr * 65536,
                                                  wattn_b + lyr * 256, qb, gT);
    // score + sigmoid/adj/eye mask -> bf16 unnormalized a
    gemm_bt<2, true, 0, false><<<dim3(8, 8, 16), 256, 0, stream>>>(
        qb, gcur, nullptr, nullptr, adj, abf, 512, 512, 256, 131072, 131072, 262144);
    rowsum_inv<<<dim3(128, 16), 256, 0, stream>>>(abf, rinv);
    // AV with row-scale epilogue (normalization commutes with the matmul)
    gemm_bt<3, true, 0, false><<<dim3(4, 8, 16), 256, 0, stream>>>(
        abf, gT, nullptr, nullptr, rinv, t1, 512, 256, 512, 262144, 131072, 131072);
    gemm_bt<1, true, 0, false><<<dim3(4, 128, 1), 256, 0, stream>>>(
        t1, wlin0_bf + lyr * 65536, lin0_b + lyr * 256, nullptr, nullptr, t2, 8192, 256, 256, 0, 0, 0);
    gemm_bt<1, true, 0, true><<<dim3(4, 128, 1), 256, 0, stream>>>(
        t2, wlin1_bf + lyr * 65536, lin1_b + lyr * 256, gcur, nullptr, gnext, 8192, 256, 256, 0, 0, 0);
    u16* tmp = gcur; gcur = gnext; gnext = tmp;
  }
  gemm_bt<0, true, 0, false><<<dim3(4, 128, 1), 256, 0, stream>>>(
      gcur, wlinf_bf, linf_b, nullptr, nullptr, t2, 8192, 256, 256, 0, 0, 0);

  // ---- pool + head ----
  mean_cat<<<16, 256, 0, stream>>>(lstm_out, t2, (float*)d_out);
  head_kernel<<<1, 256, 0, stream>>>((const float*)d_out + 32,
                                     fcA_W, fcA_b, fcB_W, fcB_b, fcC_W, fcC_b,
                                     (float*)d_out);
}

// Round 11
// 1225.119 us; speedup vs baseline: 1.8948x; 1.0052x over previous
//
#include <hip/hip_runtime.h>
#include <stdint.h>

#define B_ 16
#define S_ 512
#define D_ 1024
#define H4 512
#define G_ 256

typedef unsigned short u16;
using short8 = __attribute__((ext_vector_type(8))) short;
using f32x4  = __attribute__((ext_vector_type(4))) float;

__device__ __forceinline__ u16 f2bf(float f){
  unsigned int u = __float_as_uint(f);
  u += 0x7fffu + ((u >> 16) & 1u);
  return (u16)(u >> 16);
}
__device__ __forceinline__ float bf2f(u16 h){
  return __uint_as_float(((unsigned int)h) << 16);
}

// ---------------- single-dispatch f32 -> bf16 convert over all segments ----------------
struct CvtSegs {
  const float4* src[14];
  short4* dst[14];
  int blk0[15];
};
__global__ __launch_bounds__(256) void cvt_multi(CvtSegs cs){
  int blk = blockIdx.x;
  int s = 0;
  #pragma unroll
  for (int k = 0; k < 14; ++k) if (cs.blk0[k + 1] <= blk) s = k + 1;
  int i = (blk - cs.blk0[s]) * 256 + threadIdx.x;
  float4 v = cs.src[s][i];
  short4 o;
  o.x = (short)f2bf(v.x); o.y = (short)f2bf(v.y);
  o.z = (short)f2bf(v.z); o.w = (short)f2bf(v.w);
  cs.dst[s][i] = o;
}

// ---------------- LSTM bias sums (bih+bhh) ----------------
__global__ __launch_bounds__(256) void bias_prep(const float* a,const float* b,const float* c,const float* d,
                                                 const float* e,const float* f,const float* g,const float* h,
                                                 float* out){
  int i = blockIdx.x * 256 + threadIdx.x;
  if (i >= 2048) return;
  int p = i >> 9, k = i & 511;
  const float* x1 = (p==0)?a:(p==1)?c:(p==2)?e:g;
  const float* x2 = (p==0)?b:(p==1)?d:(p==2)?f:h;
  out[i] = x1[k] + x2[k];
}

// ---------------- MFMA BT-GEMM body (256 thr, 64x64 tile) ----------------
// EPI: 0=none, 1=relu, 2=score-mask (sigmoid+adj+eye, ex=adj), 3=row-scale (ex=rinv)
// PERM: 0 = row-major out, 2 = gate-interleaved X layout
template<int EPI, bool OUT_BF16, int PERM, bool RESID>
__device__ __forceinline__ void gemm_bt_body(
    const u16* __restrict__ A, const u16* __restrict__ W,
    const float* __restrict__ bias, const u16* __restrict__ resid,
    const float* __restrict__ ex,
    void* __restrict__ outp, int M, int N, int K,
    long sA, long sW, long sO, int bx, int by, int bz)
{
  const u16* Ab = A + (long)bz * sA;
  const u16* Wb = W + (long)bz * sW;
  const int bm0 = by * 64, bn0 = bx * 64;
  const int tid = threadIdx.x;
  const int l = tid & 63, wid = tid >> 6;
  const int wm = (wid >> 1) * 32, wn = (wid & 1) * 32;
  const int lr = l & 15, lk8 = (l >> 4) * 8;

  const f32x4 z4 = {0.f, 0.f, 0.f, 0.f};
  f32x4 acc[2][2] = {{z4, z4}, {z4, z4}};

  const u16* Ap0 = Ab + (long)(bm0 + wm + lr) * K + lk8;
  const u16* Wp0 = Wb + (long)(bn0 + wn + lr) * K + lk8;
  for (int k0 = 0; k0 < K; k0 += 32) {
    short8 a0 = *reinterpret_cast<const short8*>(Ap0 + k0);
    short8 a1 = *reinterpret_cast<const short8*>(Ap0 + (long)16 * K + k0);
    short8 b0 = *reinterpret_cast<const short8*>(Wp0 + k0);
    short8 b1 = *reinterpret_cast<const short8*>(Wp0 + (long)16 * K + k0);
    acc[0][0] = __builtin_amdgcn_mfma_f32_16x16x32_bf16(a0, b0, acc[0][0], 0, 0, 0);
    acc[0][1] = __builtin_amdgcn_mfma_f32_16x16x32_bf16(a0, b1, acc[0][1], 0, 0, 0);
    acc[1][0] = __builtin_amdgcn_mfma_f32_16x16x32_bf16(a1, b0, acc[1][0], 0, 0, 0);
    acc[1][1] = __builtin_amdgcn_mfma_f32_16x16x32_bf16(a1, b1, acc[1][1], 0, 0, 0);
  }
  #pragma unroll
  for (int mt = 0; mt < 2; ++mt)
  #pragma unroll
  for (int nt = 0; nt < 2; ++nt) {
    int n = bn0 + wn + 16 * nt + lr;
    float bv = bias ? bias[n] : 0.f;
    #pragma unroll
    for (int r = 0; r < 4; ++r) {
      int m = bm0 + wm + 16 * mt + (l >> 4) * 4 + r;
      float v = acc[mt][nt][r] + bv;
      if (EPI == 1) v = fmaxf(v, 0.f);
      if (EPI == 2) {
        float sg = __fdividef(1.f, 1.f + __expf(-v));
        v = (n == m) ? (sg + 1e-5f) : sg * ex[((long)bz * 512 + m) * 512 + n];
      }
      if (EPI == 3) v *= ex[(long)bz * 512 + m];
      if (RESID) v += bf2f(resid[(long)m * N + n]);
      long oi;
      if (PERM == 2) {
        int t = m & 511, b = m >> 9;
        oi = (long)((t * 16 + b) * 128 + (n & 127)) * 4 + (n >> 7);
      } else {
        oi = (long)bz * sO + (long)m * N + n;
      }
      if (OUT_BF16) ((u16*)outp)[oi] = f2bf(v);
      else          ((float*)outp)[oi] = v;
    }
  }
}

template<int EPI, bool OUT_BF16, int PERM, bool RESID>
__global__ __launch_bounds__(256) void gemm_bt(
    const u16* __restrict__ A, const u16* __restrict__ W,
    const float* __restrict__ bias, const u16* __restrict__ resid,
    const float* __restrict__ ex,
    void* __restrict__ outp, int M, int N, int K,
    long sA, long sW, long sO)
{
  gemm_bt_body<EPI, OUT_BF16, PERM, RESID>(A, W, bias, resid, ex, outp, M, N, K,
                                           sA, sW, sO, blockIdx.x, blockIdx.y, blockIdx.z);
}

// ---------------- fused f/b input projections (PERM2, f32 out) ----------------
__global__ __launch_bounds__(256) void proj2(
    const u16* __restrict__ A, const u16* __restrict__ W0, const u16* __restrict__ W1,
    const float* __restrict__ bias, float* __restrict__ O0, float* __restrict__ O1, int K)
{
  int z = blockIdx.z;
  gemm_bt_body<0, false, 2, false>(A, z ? W1 : W0, bias + z * 512, nullptr, nullptr,
                                   z ? O1 : O0, 8192, 512, K, 0, 0, 0,
                                   blockIdx.x, blockIdx.y, 0);
}

// ---------------- 8-wave BT-GEMM body (512 thr, 64x128 tile, bf16 out, bias) ----------------
__device__ __forceinline__ void gemm_bt_body8(
    const u16* __restrict__ A, const u16* __restrict__ W,
    const float* __restrict__ bias, u16* __restrict__ out,
    int N, int K, int bx, int by)
{
  const int bm0 = by * 64, bn0 = bx * 128;
  const int tid = threadIdx.x;
  const int l = tid & 63, wid = tid >> 6;
  const int wm = (wid >> 2) * 32, wn = (wid & 3) * 32;
  const int lr = l & 15, lk8 = (l >> 4) * 8;

  const f32x4 z4 = {0.f, 0.f, 0.f, 0.f};
  f32x4 acc[2][2] = {{z4, z4}, {z4, z4}};

  const u16* Ap0 = A + (long)(bm0 + wm + lr) * K + lk8;
  const u16* Wp0 = W + (long)(bn0 + wn + lr) * K + lk8;
  for (int k0 = 0; k0 < K; k0 += 32) {
    short8 a0 = *reinterpret_cast<const short8*>(Ap0 + k0);
    short8 a1 = *reinterpret_cast<const short8*>(Ap0 + (long)16 * K + k0);
    short8 b0 = *reinterpret_cast<const short8*>(Wp0 + k0);
    short8 b1 = *reinterpret_cast<const short8*>(Wp0 + (long)16 * K + k0);
    acc[0][0] = __builtin_amdgcn_mfma_f32_16x16x32_bf16(a0, b0, acc[0][0], 0, 0, 0);
    acc[0][1] = __builtin_amdgcn_mfma_f32_16x16x32_bf16(a0, b1, acc[0][1], 0, 0, 0);
    acc[1][0] = __builtin_amdgcn_mfma_f32_16x16x32_bf16(a1, b0, acc[1][0], 0, 0, 0);
    acc[1][1] = __builtin_amdgcn_mfma_f32_16x16x32_bf16(a1, b1, acc[1][1], 0, 0, 0);
  }
  #pragma unroll
  for (int mt = 0; mt < 2; ++mt)
  #pragma unroll
  for (int nt = 0; nt < 2; ++nt) {
    int n = bn0 + wn + 16 * nt + lr;
    float bv = bias[n];
    #pragma unroll
    for (int r = 0; r < 4; ++r) {
      int m = bm0 + wm + 16 * mt + (l >> 4) * 4 + r;
      out[(long)m * N + n] = f2bf(acc[mt][nt][r] + bv);
    }
  }
}

// ---------------- LSTM scan v9: 8 blocks (dir x 4-batch group), DENSE gates ----------------
// X: [t][b(16)][j(128)][gate(4)] f32.  Whh: [512][128] bf16 plain (rows: gate*128+j).
// 4 batches placed at A-rows {0,4,8,12}. C/D row=(lane>>4)*4+reg => lane (lr,lk) holds the
// full (i,f,g,o) quad for batch lk, col 16w+lr in acc[0..3][0]. EVERY lane does exactly one
// gate quad (no exec-masked waste). One barrier/step; h double-buffered in LDS.
__device__ __forceinline__ void lstm_scan9_body(
    const float* __restrict__ X, const u16* __restrict__ Whh,
    u16* __restrict__ Hout, int dir, int bat0)
{
  __shared__ __align__(16) u16 hbuf[2][16][136];   // [parity][A-row][j] ~8.5KB

  const int tid = threadIdx.x;
  const int l = tid & 63, w = tid >> 6;
  const int lr = l & 15, lk = l >> 4;

  // B fragments: gate g tile = Whh rows [g*128 + 16w, +16)
  short8 bfrag[4][4];
  #pragma unroll
  for (int g = 0; g < 4; ++g)
    #pragma unroll
    for (int ks = 0; ks < 4; ++ks)
      bfrag[g][ks] = *reinterpret_cast<const short8*>(
          Whh + (g * 128 + 16 * w + lr) * 128 + 32 * ks + 8 * lk);

  for (int i = tid; i < 2 * 16 * 136; i += 512) ((u16*)hbuf)[i] = 0;

  float c = 0.f;
  const f32x4 z4 = {0.f, 0.f, 0.f, 0.f};

  auto ldX = [&](int t) -> float4 {
    int ta = dir ? (S_ - 1 - t) : t;
    return *reinterpret_cast<const float4*>(
        X + (size_t)((ta * 16 + bat0 + lk) * 128 + 16 * w + lr) * 4);
  };
  float4 xA = ldX(0), xB = ldX(1), xC = ldX(2), xD;
  __syncthreads();

  auto step = [&](int t, float4& xc, float4& xt, int tload) {
    const int p = t & 1;
    short8 af[4];
    #pragma unroll
    for (int ks = 0; ks < 4; ++ks)
      af[ks] = *reinterpret_cast<const short8*>(&hbuf[p][lr][32 * ks + 8 * lk]);
    f32x4 acc[4] = {z4, z4, z4, z4};
    #pragma unroll
    for (int g = 0; g < 4; ++g)
      #pragma unroll
      for (int ks = 0; ks < 4; ++ks)
        acc[g] = __builtin_amdgcn_mfma_f32_16x16x32_bf16(af[ks], bfrag[g][ks], acc[g], 0, 0, 0);
    if (tload < S_) xt = ldX(tload);   // deep prefetch
    // ---- dense gates: one quad per lane (batch lk, col 16w+lr) ----
    float zi = acc[0][0] + xc.x;
    float zf = acc[1][0] + xc.y;
    float zg = acc[2][0] + xc.z;
    float zo = acc[3][0] + xc.w;
    float si = __fdividef(1.f, 1.f + __expf(-zi));
    float sf = __fdividef(1.f, 1.f + __expf(-zf));
    float so = __fdividef(1.f, 1.f + __expf(-zo));
    float eg = __expf(2.f * zg);
    float tg = 1.f - __fdividef(2.f, eg + 1.f);
    c = sf * c + si * tg;
    float ec = __expf(2.f * c);
    float tc = 1.f - __fdividef(2.f, ec + 1.f);
    u16 hb = f2bf(so * tc);
    int ta = dir ? (S_ - 1 - t) : t;
    hbuf[p ^ 1][4 * lk][16 * w + lr] = hb;       // batch lk -> A-row 4*lk
    Hout[((size_t)(bat0 + lk) * S_ + ta) * 256 + dir * 128 + 16 * w + lr] = hb;
    asm volatile("s_waitcnt lgkmcnt(0)" ::: "memory");
    __builtin_amdgcn_s_barrier();
  };

  for (int t = 0; t < S_; t += 4) {
    step(t,     xA, xD, t + 3);
    step(t + 1, xB, xA, t + 4);
    step(t + 2, xC, xB, t + 5);
    step(t + 3, xD, xC, t + 6);
  }
}

// ---------------- fused dispatch: blocks 0..7 = scan(dir,batgrp), blocks 8.. = BT-GEMM ----------------
__global__ __launch_bounds__(512, 1) void scan_fused(
    const float* __restrict__ Xf, const float* __restrict__ Xb,
    const u16* __restrict__ Whhf, const u16* __restrict__ Whhb,
    u16* __restrict__ Hout,
    const u16* __restrict__ gA, const u16* __restrict__ gW,
    const float* __restrict__ gb, u16* __restrict__ gOut, int gK)
{
  if (blockIdx.x < 8) {
    int dir = blockIdx.x & 1, bat0 = (blockIdx.x >> 1) * 4;
    lstm_scan9_body(dir ? Xb : Xf, dir ? Whhb : Whhf, Hout, dir, bat0);
  } else {
    int bi = blockIdx.x - 8;
    gemm_bt_body8(gA, gW, gb, gOut, 256, gK, bi & 1, bi >> 1);
  }
}

// ---------------- transpose body + kernels ----------------
__device__ __forceinline__ void transpose_body(const u16* __restrict__ in, u16* __restrict__ out,
                                               int bz, int s0, int d0)
{
  __shared__ u16 tile[32][33];
  int tx = threadIdx.x & 31, ty = threadIdx.x >> 5;
  const u16* ip = in + (long)bz * 512 * 256;
  u16* op = out + (long)bz * 256 * 512;
  #pragma unroll
  for (int k = 0; k < 32; k += 8) tile[ty + k][tx] = ip[(long)(s0 + ty + k) * 256 + d0 + tx];
  __syncthreads();
  #pragma unroll
  for (int k = 0; k < 32; k += 8) op[(long)(d0 + ty + k) * 512 + s0 + tx] = tile[tx][ty + k];
}

__global__ __launch_bounds__(256) void transpose_g(const u16* __restrict__ in, u16* __restrict__ out)
{
  transpose_body(in, out, blockIdx.z, blockIdx.x * 32, blockIdx.y * 32);
}

// wattn GEMM (512 blocks) || transpose (2048 blocks), both read gcur
__global__ __launch_bounds__(256) void wattn_trans(
    const u16* __restrict__ gcur, const u16* __restrict__ wW, const float* __restrict__ wb,
    u16* __restrict__ qb, u16* __restrict__ gT)
{
  if (blockIdx.x < 512) {
    int b = blockIdx.x;
    gemm_bt_body<0, true, 0, false>(gcur, wW, wb, nullptr, nullptr, qb,
                                    8192, 256, 256, 0, 0, 0, b & 3, b >> 2, 0);
  } else {
    int b = blockIdx.x - 512;
    int bz = b >> 7, rem = b & 127;
    transpose_body(gcur, gT, bz, (rem & 15) * 32, (rem >> 4) * 32);
  }
}

// ---------------- row-sum reciprocal of masked scores ----------------
__global__ __launch_bounds__(256) void rowsum_inv(const u16* __restrict__ abf, float* __restrict__ rinv)
{
  int bz = blockIdx.y;
  int row = blockIdx.x * 4 + (threadIdx.x >> 6);
  int l = threadIdx.x & 63;
  short8 v = *reinterpret_cast<const short8*>(abf + ((size_t)bz * 512 + row) * 512 + l * 8);
  float s = 0.f;
  #pragma unroll
  for (int k = 0; k < 8; ++k) s += bf2f((u16)v[k]);
  #pragma unroll
  for (int off = 32; off; off >>= 1) s += __shfl_xor(s, off);
  if (l == 0) rinv[bz * 512 + row] = __fdividef(1.f, s);
}

// ---------------- mean over S of concat[lstm_out, g_final] -> d_out[32..] ----------------
__global__ __launch_bounds__(256) void mean_cat(
    const u16* __restrict__ lstm, const u16* __restrict__ gf, float* __restrict__ dout)
{
  int b = blockIdx.x;
  for (int cc = threadIdx.x; cc < 512; cc += 256) {
    const u16* src = (cc < 256) ? (lstm + (long)b * 512 * 256 + cc)
                                : (gf   + (long)b * 512 * 256 + (cc - 256));
    float s = 0.f;
    for (int t = 0; t < 512; ++t) s += bf2f(src[(long)t * 256]);
    dout[32 + b * 512 + cc] = s * (1.f / 512.f);
  }
}

// ---------------- head: fcA -> leaky -> fcB -> leaky -> fcC ----------------
__global__ __launch_bounds__(256) void head_kernel(
    const float* __restrict__ hidden,
    const float* __restrict__ fcA_W, const float* __restrict__ fcA_b,
    const float* __restrict__ fcB_W, const float* __restrict__ fcB_b,
    const float* __restrict__ fcC_W, const float* __restrict__ fcC_b,
    float* __restrict__ y)
{
  __shared__ float hb[16 * 512];
  __shared__ float ab[16 * 128];
  __shared__ float bb[16 * 32];
  int tid = threadIdx.x;
  for (int i = tid; i < 8192; i += 256) hb[i] = hidden[i];
  __syncthreads();
  for (int o = tid; o < 2048; o += 256) {
    int b = o >> 7, jj = o & 127;
    float acc = fcA_b[jj];
    const float* wrow = fcA_W + jj * 512;
    const float* hrow = hb + b * 512;
    for (int k = 0; k < 512; ++k) acc += hrow[k] * wrow[k];
    ab[o] = acc > 0.f ? acc : 0.1f * acc;
  }
  __syncthreads();
  for (int o = tid; o < 512; o += 256) {
    int b = o >> 5, jj = o & 31;
    float acc = fcB_b[jj];
    for (int k = 0; k < 128; ++k) acc += ab[b * 128 + k] * fcB_W[jj * 128 + k];
    bb[o] = acc > 0.f ? acc : 0.1f * acc;
  }
  __syncthreads();
  if (tid < 32) {
    int b = tid >> 1, jj = tid & 1;
    float acc = fcC_b[jj];
    for (int k = 0; k < 32; ++k) acc += bb[b * 32 + k] * fcC_W[jj * 32 + k];
    y[b * 2 + jj] = acc;
  }
}

extern "C" void kernel_launch(void* const* d_in, const int* in_sizes, int n_in,
                              void* d_out, int out_size, void* d_ws, size_t ws_size,
                              hipStream_t stream)
{
  const float* x       = (const float*)d_in[0];
  const float* adj     = (const float*)d_in[1];
  const float* l0f_Wih = (const float*)d_in[2];
  const float* l0f_Whh = (const float*)d_in[3];
  const float* l0f_bih = (const float*)d_in[4];
  const float* l0f_bhh = (const float*)d_in[5];
  const float* l0b_Wih = (const float*)d_in[6];
  const float* l0b_Whh = (const float*)d_in[7];
  const float* l0b_bih = (const float*)d_in[8];
  const float* l0b_bhh = (const float*)d_in[9];
  const float* l1f_Wih = (const float*)d_in[10];
  const float* l1f_Whh = (const float*)d_in[11];
  const float* l1f_bih = (const float*)d_in[12];
  const float* l1f_bhh = (const float*)d_in[13];
  const float* l1b_Wih = (const float*)d_in[14];
  const float* l1b_Whh = (const float*)d_in[15];
  const float* l1b_bih = (const float*)d_in[16];
  const float* l1b_bhh = (const float*)d_in[17];
  const float* fc1_W   = (const float*)d_in[18];
  const float* fc1_b   = (const float*)d_in[19];
  const float* wattn_W = (const float*)d_in[20];
  const float* wattn_b = (const float*)d_in[21];
  const float* lin0_W  = (const float*)d_in[22];
  const float* lin0_b  = (const float*)d_in[23];
  const float* lin1_W  = (const float*)d_in[24];
  const float* lin1_b  = (const float*)d_in[25];
  const float* linf_W  = (const float*)d_in[26];
  const float* linf_b  = (const float*)d_in[27];
  const float* fcA_W   = (const float*)d_in[28];
  const float* fcA_b   = (const float*)d_in[29];
  const float* fcB_W   = (const float*)d_in[30];
  const float* fcB_b   = (const float*)d_in[31];
  const float* fcC_W   = (const float*)d_in[32];
  const float* fcC_b   = (const float*)d_in[33];

  char* wp = (char*)d_ws;
  auto alloc = [&](size_t n) -> void* { void* p = wp; wp += (n + 255) & ~(size_t)255; return p; };

  u16* x_bf     = (u16*)alloc((size_t)B_ * S_ * D_ * 2);
  u16* w0f_ih   = (u16*)alloc((size_t)512 * 1024 * 2);
  u16* w0b_ih   = (u16*)alloc((size_t)512 * 1024 * 2);
  u16* w1f_ih   = (u16*)alloc((size_t)512 * 256 * 2);
  u16* w1b_ih   = (u16*)alloc((size_t)512 * 256 * 2);
  u16* w0f_hh   = (u16*)alloc((size_t)512 * 128 * 2);
  u16* w0b_hh   = (u16*)alloc((size_t)512 * 128 * 2);
  u16* w1f_hh   = (u16*)alloc((size_t)512 * 128 * 2);
  u16* w1b_hh   = (u16*)alloc((size_t)512 * 128 * 2);
  u16* wfc1     = (u16*)alloc((size_t)256 * 1024 * 2);
  u16* wattn_bf = (u16*)alloc((size_t)4 * 256 * 256 * 2);
  u16* wlin0_bf = (u16*)alloc((size_t)4 * 256 * 256 * 2);
  u16* wlin1_bf = (u16*)alloc((size_t)4 * 256 * 256 * 2);
  u16* wlinf_bf = (u16*)alloc((size_t)256 * 256 * 2);
  float* bias4  = (float*)alloc((size_t)2048 * 4);
  float* X0f    = (float*)alloc((size_t)S_ * 16 * 512 * 4);
  float* X0b    = (float*)alloc((size_t)S_ * 16 * 512 * 4);
  u16* h0       = (u16*)alloc((size_t)B_ * S_ * 256 * 2);
  u16* lstm_out = (u16*)alloc((size_t)B_ * S_ * 256 * 2);
  u16* gA       = (u16*)alloc((size_t)B_ * S_ * 256 * 2);
  u16* gB       = (u16*)alloc((size_t)B_ * S_ * 256 * 2);
  u16* qb       = (u16*)alloc((size_t)B_ * S_ * 256 * 2);
  u16* gT       = (u16*)alloc((size_t)B_ * S_ * 256 * 2);
  u16* t1       = (u16*)alloc((size_t)B_ * S_ * 256 * 2);
  u16* t2       = (u16*)alloc((size_t)B_ * S_ * 256 * 2);
  u16* abf      = (u16*)alloc((size_t)B_ * S_ * S_ * 2);
  float* rinv   = (float*)alloc((size_t)B_ * S_ * 4);

  // ---- conversions (14 segments) ----
  CvtSegs cs;
  int nb = 0, si = 0;
  auto seg = [&](const float* s, u16* d, int n) {
    cs.src[si] = (const float4*)s; cs.dst[si] = (short4*)d;
    cs.blk0[si] = nb; nb += (n / 4 + 255) / 256; ++si;
  };
  seg(x, x_bf, B_ * S_ * D_);
  seg(l0f_Wih, w0f_ih, 512 * 1024);
  seg(l0b_Wih, w0b_ih, 512 * 1024);
  seg(l1f_Wih, w1f_ih, 512 * 256);
  seg(l1b_Wih, w1b_ih, 512 * 256);
  seg(l0f_Whh, w0f_hh, 512 * 128);
  seg(l0b_Whh, w0b_hh, 512 * 128);
  seg(l1f_Whh, w1f_hh, 512 * 128);
  seg(l1b_Whh, w1b_hh, 512 * 128);
  seg(fc1_W, wfc1, 256 * 1024);
  seg(wattn_W, wattn_bf, 4 * 256 * 256);
  seg(lin0_W, wlin0_bf, 4 * 256 * 256);
  seg(lin1_W, wlin1_bf, 4 * 256 * 256);
  seg(linf_W, wlinf_bf, 256 * 256);
  for (int k = si; k <= 14; ++k) cs.blk0[k] = nb;
  cvt_multi<<<nb, 256, 0, stream>>>(cs);
  bias_prep<<<8, 256, 0, stream>>>(l0f_bih, l0f_bhh, l0b_bih, l0b_bhh,
                                   l1f_bih, l1f_bhh, l1b_bih, l1b_bhh, bias4);

  // ---- LSTM layer 0: fused f/b projections, then scan (+fc1 GEMM fused) ----
  proj2<<<dim3(8, 128, 2), 256, 0, stream>>>(x_bf, w0f_ih, w0b_ih, bias4, X0f, X0b, 1024);
  scan_fused<<<8 + 256, 512, 0, stream>>>(X0f, X0b, w0f_hh, w0b_hh, h0,
                                          x_bf, wfc1, fc1_b, gA, 1024);
  // ---- LSTM layer 1 (+ GAT layer-0 wattn GEMM fused) ----
  proj2<<<dim3(8, 128, 2), 256, 0, stream>>>(h0, w1f_ih, w1b_ih, bias4 + 1024, X0f, X0b, 256);
  scan_fused<<<8 + 256, 512, 0, stream>>>(X0f, X0b, w1f_hh, w1b_hh, lstm_out,
                                          gA, wattn_bf, wattn_b, qb, 256);

  // ---- GAT ----
  u16* gcur = gA; u16* gnext = gB;
  for (int lyr = 0; lyr < 4; ++lyr) {
    if (lyr == 0)
      transpose_g<<<dim3(16, 8, 16), 256, 0, stream>>>(gcur, gT);
    else
      wattn_trans<<<512 + 2048, 256, 0, stream>>>(gcur, wattn_bf + lyr * 65536,
                                                  wattn_b + lyr * 256, qb, gT);
    // score + sigmoid/adj/eye mask -> bf16 unnormalized a
    gemm_bt<2, true, 0, false><<<dim3(8, 8, 16), 256, 0, stream>>>(
        qb, gcur, nullptr, nullptr, adj, abf, 512, 512, 256, 131072, 131072, 262144);
    rowsum_inv<<<dim3(128, 16), 256, 0, stream>>>(abf, rinv);
    // AV with row-scale epilogue (normalization commutes with the matmul)
    gemm_bt<3, true, 0, false><<<dim3(4, 8, 16), 256, 0, stream>>>(
        abf, gT, nullptr, nullptr, rinv, t1, 512, 256, 512, 262144, 131072, 131072);
    gemm_bt<1, true, 0, false><<<dim3(4, 128, 1), 256, 0, stream>>>(
        t1, wlin0_bf + lyr * 65536, lin0_b + lyr * 256, nullptr, nullptr, t2, 8192, 256, 256, 0, 0, 0);
    gemm_bt<1, true, 0, true><<<dim3(4, 128, 1), 256, 0, stream>>>(
        t2, wlin1_bf + lyr * 65536, lin1_b + lyr * 256, gcur, nullptr, gnext, 8192, 256, 256, 0, 0, 0);
    u16* tmp = gcur; gcur = gnext; gnext = tmp;
  }
  gemm_bt<0, true, 0, false><<<dim3(4, 128, 1), 256, 0, stream>>>(
      gcur, wlinf_bf, linf_b, nullptr, nullptr, t2, 8192, 256, 256, 0, 0, 0);

  // ---- pool + head ----
  mean_cat<<<16, 256, 0, stream>>>(lstm_out, t2, (float*)d_out);
  head_kernel<<<1, 256, 0, stream>>>((const float*)d_out + 32,
                                     fcA_W, fcA_b, fcB_W, fcB_b, fcC_W, fcC_b,
                                     (float*)d_out);
}